// Round 9
// baseline (303.808 us; speedup 1.0000x reference)
//
#include <hip/hip_runtime.h>
#include <hip/hip_bf16.h>
#include <stdint.h>

// MultiHeadAttention: B=8, S=1024, D=1024, H=16, DH=64. fp32 in/out (auto-detects bf16).
// Round-17: qkv rebuilt as the 8-phase 256x256 counted-vmcnt template (T3+T4+T5).
// BK=64, 8 waves (2Mx4N), LDS 128KB = 2buf x 2khalf x {A,B} x 256rows x 64B.
// Phase = (kk, mihalf): 16 MFMA, 8/4 ds_read_b128, 1 khalf-tile staged (2 dma16).
// Staging placed in earliest phase after target LDS region fully consumed (race-free
// by consumption-order analysis); vmcnt(6) at ph4/ph8 only (never 0 in main loop);
// prologue 7 half-tiles + vmcnt(6); final iter vmcnt(0) at ph4. Raw s_barrier +
// compiler lgkmcnt (no inline-asm LDS reads). grid (32,12)=384.
// attn/prep/out unchanged from r16 best (289.6us): attn de-lockstep 8w x 32q,
// prep mask-pack 1536 blocks, out 128^2 grid(64,8).
// ws layout A (>=74MB): WT@0(6) WoT@6(2) bits@8(1) bc@9 Xb@10(16,reused as ctx) Q@26 K@42 Vt@58
// ws layout B (<74MB):  raw-X fallback gemm; ctx in d_out; emit kernel.

typedef __attribute__((ext_vector_type(8))) short short8;
typedef __attribute__((ext_vector_type(4))) float floatx4;

#define C2S 0.04508422f   // (1/sqrt(1024)) * log2(e), folded into Q

__device__ __forceinline__ int swz(int r, int kc) { return r * 8 + (kc ^ (r & 7)); }
__device__ __forceinline__ short8 as_frag(uint4 u) { return __builtin_bit_cast(short8, u); }
__device__ __forceinline__ floatx4 mfma16(short8 a, short8 b, floatx4 c) {
    return __builtin_amdgcn_mfma_f32_16x16x32_bf16(a, b, c, 0, 0, 0);
}
__device__ __forceinline__ unsigned short f2bu(float f) {
    return __builtin_bit_cast(unsigned short, __float2bfloat16(f));
}
__device__ __forceinline__ short f2b(float f) {
    return __builtin_bit_cast(short, __float2bfloat16(f));
}
__device__ __forceinline__ float b2f(short s) {
    return __bfloat162float(__builtin_bit_cast(__hip_bfloat16, s));
}
// async global->LDS DMA, 16B per lane; lds dest = wave-uniform base + lane*16
__device__ __forceinline__ void dma16(const void* g, void* l) {
    __builtin_amdgcn_global_load_lds(
        (const __attribute__((address_space(1))) uint32_t*)g,
        (__attribute__((address_space(3))) uint32_t*)l, 16, 0, 0);
}
__device__ __forceinline__ uint2 pack4(float a, float b, float c, float d) {
    uint2 p;
    p.x = (unsigned)f2bu(a) | ((unsigned)f2bu(b) << 16);
    p.y = (unsigned)f2bu(c) | ((unsigned)f2bu(d) << 16);
    return p;
}

// Runtime dtype detection: bf16 data has sane exponents in the LOW halves of
// 32-bit words; fp32 data has uniform mantissa bits there.
__device__ __forceinline__ void detect_mode(const unsigned* Xw, int* s_is32) {
    if (threadIdx.x < 64) {
        unsigned lo = Xw[threadIdx.x] & 0xFFFFu;
        unsigned e = (lo >> 7) & 0xFFu;
        unsigned long long bal = __ballot(e >= 88u && e <= 150u);
        if (threadIdx.x == 0) *s_is32 = (bal != ~0ull) ? 1 : 0;
    }
    __syncthreads();
}

__device__ __forceinline__ float load_elt(const void* p, size_t idx, int is32) {
    return is32 ? ((const float*)p)[idx]
                : __bfloat162float(((const __hip_bfloat16*)p)[idx]);
}

// ---------------------------------------------------------------- fused prep
// blocks [0,1024): weight transpose (vectorized); [1024]: biases;
// [1025,2561): mask pack (t-major, 1536 blocks); [2561,4609): X convert.
__global__ __launch_bounds__(256) void prep_all(
    const void* __restrict__ Wq, const void* __restrict__ Wk,
    const void* __restrict__ Wv, const void* __restrict__ Wo,
    const void* __restrict__ bq, const void* __restrict__ bk,
    const void* __restrict__ bv, const void* __restrict__ bo,
    const void* __restrict__ mask_raw, const void* __restrict__ X,
    __hip_bfloat16* __restrict__ WT, __hip_bfloat16* __restrict__ WoT,
    __hip_bfloat16* __restrict__ bc, unsigned long long* __restrict__ bits64,
    __hip_bfloat16* __restrict__ Xb, int do_x)
{
    __shared__ __hip_bfloat16 T[64][72];
    __shared__ int s_is32;
    int blk = blockIdx.x;
    int tid = threadIdx.x;
    const unsigned* Xw = (const unsigned*)X;

    if (blk < 1024) {                           // ---- weight transpose (vectorized)
        detect_mode(Xw, &s_is32);
        const void* src; size_t src_off;
        __hip_bfloat16* dst;
        int src_ld, dst_ld;
        if (blk < 768) {                        // Wq/Wk/Wv: [h][d][e] -> WT[(p,h,e)][d]
            int p = blk >> 8;
            int rem = blk & 255;
            int h = rem >> 4, dt = rem & 15;
            src = (p == 0) ? Wq : (p == 1) ? Wk : Wv;
            src_off = ((size_t)h * 1024 + (size_t)dt * 64) * 64;
            dst = WT + (((size_t)p * 16 + h) * 64) * 1024 + dt * 64;
            src_ld = 64; dst_ld = 1024;
        } else {                                // Wo: [k][n] -> WoT[n][k]
            int t = blk - 768;
            int kt = t >> 4, nt = t & 15;
            src = Wo; src_off = (size_t)kt * 64 * 1024 + nt * 64;
            dst = WoT + (size_t)nt * 64 * 1024 + kt * 64;
            src_ld = 1024; dst_ld = 1024;
        }
        #pragma unroll
        for (int i = 0; i < 2; i++) {
            int seg = tid + i * 256;
            int r = seg >> 3, c0 = (seg & 7) * 8;
            if (s_is32) {
                const float* sf = (const float*)src + src_off + (size_t)r * src_ld + c0;
                float4 f0 = *(const float4*)sf;
                float4 f1 = *(const float4*)(sf + 4);
                T[c0 + 0][r] = __float2bfloat16(f0.x);
                T[c0 + 1][r] = __float2bfloat16(f0.y);
                T[c0 + 2][r] = __float2bfloat16(f0.z);
                T[c0 + 3][r] = __float2bfloat16(f0.w);
                T[c0 + 4][r] = __float2bfloat16(f1.x);
                T[c0 + 5][r] = __float2bfloat16(f1.y);
                T[c0 + 6][r] = __float2bfloat16(f1.z);
                T[c0 + 7][r] = __float2bfloat16(f1.w);
            } else {
                const __hip_bfloat16* sh =
                    (const __hip_bfloat16*)src + src_off + (size_t)r * src_ld + c0;
                uint4 u = *(const uint4*)sh;
                short8 s8 = __builtin_bit_cast(short8, u);
                #pragma unroll
                for (int j = 0; j < 8; j++)
                    T[c0 + j][r] = __builtin_bit_cast(__hip_bfloat16, (short)s8[j]);
            }
        }
        __syncthreads();
        #pragma unroll
        for (int i = 0; i < 2; i++) {
            int seg = tid + i * 256;
            int r = seg >> 3, c0 = (seg & 7) * 8;
            *(uint4*)(dst + (size_t)r * dst_ld + c0) = *(const uint4*)(&T[r][c0]);
        }
    } else if (blk == 1024) {                   // ---- biases (bq prescaled by C2S)
        detect_mode(Xw, &s_is32);
        #pragma unroll
        for (int i = 0; i < 16; i++) {
            int idx = tid + i * 256;
            int which = idx >> 10, j = idx & 1023;
            const void* src = (which == 0) ? bq : (which == 1) ? bk : (which == 2) ? bv : bo;
            float v = load_elt(src, j, s_is32);
            if (which == 0) v *= C2S;
            bc[idx] = __float2bfloat16(v);
        }
    } else if (blk < 2561) {                    // ---- mask pack (1536 blocks), t-major out
        int blkL = blk - 1025;
        const int* mi = (const int*)mask_raw;
        const unsigned char* mb = (const unsigned char*)mask_raw;
        int lane = tid & 63;
        bool ok = true;
        #pragma unroll
        for (int i = 0; i < 4; i++) {
            unsigned v = (unsigned)mi[lane * 4 + i];
            if (v > 1u) ok = false;
        }
        bool is_i32 = (__ballot(ok) == ~0ull);
        int gw = (blkL * 256 + tid) >> 6;
        const int NW = 1536 * 4;
        const int NWORDS = (8 * 1024 * 1024) / 64;
        // src word i = (b*1024 + q)*16 + t  ->  dst (b*16 + t)*1024 + q
        if (is_i32) {
            for (int i = gw; i < NWORDS; i += NW) {
                int mv = mi[(size_t)i * 64 + lane];
                unsigned long long bal = __ballot(mv != 0);
                if (lane == 0) {
                    int bb = i >> 14, q = (i >> 4) & 1023, t = i & 15;
                    bits64[((size_t)bb << 14) + ((size_t)t << 10) + q] = bal;
                }
            }
        } else {
            for (int i = gw; i < NWORDS; i += NW) {
                int mv = mb[(size_t)i * 64 + lane];
                unsigned long long bal = __ballot(mv != 0);
                if (lane == 0) {
                    int bb = i >> 14, q = (i >> 4) & 1023, t = i & 15;
                    bits64[((size_t)bb << 14) + ((size_t)t << 10) + q] = bal;
                }
            }
        }
    } else if (do_x) {                          // ---- X convert (2048 blocks)
        detect_mode(Xw, &s_is32);
        int blkL = blk - 2561;
        size_t g = ((size_t)blkL * 256 + tid) * 16;
        if (s_is32) {
            const float* Xf = (const float*)X;
            #pragma unroll
            for (int half = 0; half < 2; half++) {
                float4 f0 = *(const float4*)(Xf + g + half * 8);
                float4 f1 = *(const float4*)(Xf + g + half * 8 + 4);
                short8 s;
                s[0] = f2b(f0.x); s[1] = f2b(f0.y); s[2] = f2b(f0.z); s[3] = f2b(f0.w);
                s[4] = f2b(f1.x); s[5] = f2b(f1.y); s[6] = f2b(f1.z); s[7] = f2b(f1.w);
                *(uint4*)(Xb + g + half * 8) = __builtin_bit_cast(uint4, s);
            }
        } else {
            const uint4* Xu = (const uint4*)X;
            *(uint4*)(Xb + g)     = Xu[g / 8];
            *(uint4*)(Xb + g + 8) = Xu[g / 8 + 1];
        }
    }
}

// ---------------------------------------------------------------- QKV GEMM (8-phase)
// C[8192 m, 3072 n] = Xb @ WT^T. 256x256 tiles, BK=64, grid (32 m, 12 n), 8 waves.
// LDS layout: [buf*2+kh][row][slot], slot = chunk ^ (row&3), chunk = 8 bf16 = 16B.
// Phase = (kk, mihalf): 16 MFMA; B-frags loaded at mihalf 0, carried to mihalf 1.
// Staging: 1 khalf-tile (2 dma16/wave) per phase, earliest-safe placement;
// vmcnt(6) at ph4/ph8 (counted, never drains); proj-0 scaled by C2S.
#define VM6 asm volatile("s_waitcnt vmcnt(6)" ::: "memory")
#define VM0 asm volatile("s_waitcnt vmcnt(0)" ::: "memory")
#define FENCE asm volatile("" ::: "memory")

#define QPH(BUF, KK, MH, LOADB, STAGE_STMT, WAIT_STMT)                          \
  {                                                                             \
    const int base_ = ((BUF) * 2 + (KK)) * 1024;                                \
    short8 af0 = as_frag(AsU[base_ + (mw * 128 + ((MH) * 4 + 0) * 16 + ln) * 4 + rslot]); \
    short8 af1 = as_frag(AsU[base_ + (mw * 128 + ((MH) * 4 + 1) * 16 + ln) * 4 + rslot]); \
    short8 af2 = as_frag(AsU[base_ + (mw * 128 + ((MH) * 4 + 2) * 16 + ln) * 4 + rslot]); \
    short8 af3 = as_frag(AsU[base_ + (mw * 128 + ((MH) * 4 + 3) * 16 + ln) * 4 + rslot]); \
    if (LOADB) {                                                                \
      bf[0] = as_frag(BsU[base_ + (nw * 64 + 0 * 16 + ln) * 4 + rslot]);        \
      bf[1] = as_frag(BsU[base_ + (nw * 64 + 1 * 16 + ln) * 4 + rslot]);        \
      bf[2] = as_frag(BsU[base_ + (nw * 64 + 2 * 16 + ln) * 4 + rslot]);        \
      bf[3] = as_frag(BsU[base_ + (nw * 64 + 3 * 16 + ln) * 4 + rslot]);        \
    }                                                                           \
    STAGE_STMT;                                                                 \
    FENCE; __builtin_amdgcn_s_barrier(); FENCE;                                 \
    __builtin_amdgcn_s_setprio(1);                                              \
    acc[(MH) * 4 + 0][0] = mfma16(af0, bf[0], acc[(MH) * 4 + 0][0]);            \
    acc[(MH) * 4 + 0][1] = mfma16(af0, bf[1], acc[(MH) * 4 + 0][1]);            \
    acc[(MH) * 4 + 0][2] = mfma16(af0, bf[2], acc[(MH) * 4 + 0][2]);            \
    acc[(MH) * 4 + 0][3] = mfma16(af0, bf[3], acc[(MH) * 4 + 0][3]);            \
    acc[(MH) * 4 + 1][0] = mfma16(af1, bf[0], acc[(MH) * 4 + 1][0]);            \
    acc[(MH) * 4 + 1][1] = mfma16(af1, bf[1], acc[(MH) * 4 + 1][1]);            \
    acc[(MH) * 4 + 1][2] = mfma16(af1, bf[2], acc[(MH) * 4 + 1][2]);            \
    acc[(MH) * 4 + 1][3] = mfma16(af1, bf[3], acc[(MH) * 4 + 1][3]);            \
    acc[(MH) * 4 + 2][0] = mfma16(af2, bf[0], acc[(MH) * 4 + 2][0]);            \
    acc[(MH) * 4 + 2][1] = mfma16(af2, bf[1], acc[(MH) * 4 + 2][1]);            \
    acc[(MH) * 4 + 2][2] = mfma16(af2, bf[2], acc[(MH) * 4 + 2][2]);            \
    acc[(MH) * 4 + 2][3] = mfma16(af2, bf[3], acc[(MH) * 4 + 2][3]);            \
    acc[(MH) * 4 + 3][0] = mfma16(af3, bf[0], acc[(MH) * 4 + 3][0]);            \
    acc[(MH) * 4 + 3][1] = mfma16(af3, bf[1], acc[(MH) * 4 + 3][1]);            \
    acc[(MH) * 4 + 3][2] = mfma16(af3, bf[2], acc[(MH) * 4 + 3][2]);            \
    acc[(MH) * 4 + 3][3] = mfma16(af3, bf[3], acc[(MH) * 4 + 3][3]);            \
    __builtin_amdgcn_s_setprio(0);                                              \
    WAIT_STMT;                                                                  \
    FENCE; __builtin_amdgcn_s_barrier(); FENCE;                                 \
  }

__global__ __launch_bounds__(512, 2) void qkv_gemm_dma(
    const __hip_bfloat16* __restrict__ Xb,   // [8192][1024] bf16
    const __hip_bfloat16* __restrict__ WT,   // [3072 n][1024 k]
    const __hip_bfloat16* __restrict__ bc,   // [4][1024]
    __hip_bfloat16* __restrict__ Q,
    __hip_bfloat16* __restrict__ Ko,
    __hip_bfloat16* __restrict__ Vt)
{
    __shared__ uint4 AsU[4096];   // 64 KB: [buf*2+kh][256 rows][4 slots]
    __shared__ uint4 BsU[4096];   // 64 KB
    int tid = threadIdx.x, lane = tid & 63, w = tid >> 6;   // 8 waves
    int quad = lane >> 4, ln = lane & 15;
    int mw = w & 1, nw = w >> 1;                            // 2M x 4N
    int m0 = blockIdx.x * 256;
    int n0 = blockIdx.y * 256;
    const __hip_bfloat16* Wp = WT + (size_t)n0 * 1024;

    // staging geometry: issue j covers rows (w*2+j)*16 + (lane>>2), slot lane&3;
    // source chunk pre-swizzled: kcS = slot ^ (row&3) = (lane&3) ^ ((lane>>2)&3)
    int l2 = lane >> 2;
    int kcS = (lane & 3) ^ (l2 & 3);
    // frag-read slot: row&3 == ln&3
    int rslot = quad ^ (ln & 3);

    floatx4 acc[8][4];
    #pragma unroll
    for (int i = 0; i < 8; i++)
        #pragma unroll
        for (int j = 0; j < 4; j++) acc[i][j] = (floatx4){0.f, 0.f, 0.f, 0.f};

    auto stA = [&](int kt, int kh) {
        int kh2 = (kt & 1) * 2 + kh;
        #pragma unroll
        for (int j = 0; j < 2; j++) {
            int r = (w * 2 + j) * 16 + l2;
            dma16(Xb + (size_t)(m0 + r) * 1024 + kt * 64 + kh * 32 + kcS * 8,
                  (char*)AsU + (size_t)(kh2 * 1024 + (w * 2 + j) * 64) * 16);
        }
    };
    auto stB = [&](int kt, int kh) {
        int kh2 = (kt & 1) * 2 + kh;
        #pragma unroll
        for (int j = 0; j < 2; j++) {
            int r = (w * 2 + j) * 16 + l2;
            dma16(Wp + (size_t)r * 1024 + kt * 64 + kh * 32 + kcS * 8,
                  (char*)BsU + (size_t)(kh2 * 1024 + (w * 2 + j) * 64) * 16);
        }
    };

    // prologue: tile0 fully + tile1's first 3 khalf-tiles (A(1)kh1 staged in ph1)
    stB(0, 0); stA(0, 0); stB(0, 1); stA(0, 1);
    stB(1, 0); stA(1, 0); stB(1, 1);
    VM6;                          // tile0's 4 half-tiles landed (last 3 may fly)
    FENCE; __builtin_amdgcn_s_barrier(); FENCE;

    short8 bf[4];
    for (int it = 0; it < 8; it++) {
        int T = 2 * it;
        bool more = (it < 7);
        QPH(0, 0, 0, 1, { stA(T + 1, 1); },              {})                  // ph1
        QPH(0, 0, 1, 0, { if (more) stB(T + 2, 0); },    {})                  // ph2
        QPH(0, 1, 0, 1, { if (more) stA(T + 2, 0); },    {})                  // ph3
        QPH(0, 1, 1, 0, { if (more) stB(T + 2, 1); },
            { if (more) { VM6; } else { VM0; } })                             // ph4
        QPH(1, 0, 0, 1, { if (more) stA(T + 2, 1); },    {})                  // ph5
        QPH(1, 0, 1, 0, { if (more) stB(T + 3, 0); },    {})                  // ph6
        QPH(1, 1, 0, 1, { if (more) stA(T + 3, 0); },    {})                  // ph7
        QPH(1, 1, 1, 0, { if (more) stB(T + 3, 1); },
            { if (more) { VM6; } })                                           // ph8
    }

    int b = m0 >> 10;
    int s0 = m0 & 1023;
    int proj = n0 >> 10;                     // uniform per block (256 | 1024)
    if (proj == 2) {
        #pragma unroll
        for (int ni = 0; ni < 4; ni++) {
            int n = n0 + nw * 64 + ni * 16 + ln;
            int h = (n >> 6) & 15, e = n & 63;
            float bval = __bfloat162float(bc[2 * 1024 + (n & 1023)]);
            #pragma unroll
            for (int mi = 0; mi < 8; mi++) {
                int sb = s0 + mw * 128 + mi * 16 + quad * 4;
                uint2 pk = pack4(acc[mi][ni][0] + bval, acc[mi][ni][1] + bval,
                                 acc[mi][ni][2] + bval, acc[mi][ni][3] + bval);
                *(uint2*)(Vt + (((size_t)b * 16 + h) * 64 + e) * 1024 + sb) = pk;
            }
        }
    } else {
        __hip_bfloat16* P = (proj == 0) ? Q : Ko;
        float sc = (proj == 0) ? C2S : 1.f;   // fold attn scale*log2e into Q
        #pragma unroll
        for (int ni = 0; ni < 4; ni++) {
            int n = n0 + nw * 64 + ni * 16 + ln;
            int h = (n >> 6) & 15, e = n & 63;
            float bval = __bfloat162float(bc[proj * 1024 + (n & 1023)]);
            #pragma unroll
            for (int mi = 0; mi < 8; mi++) {
                #pragma unroll
                for (int r = 0; r < 4; r++) {
                    int s = s0 + mw * 128 + mi * 16 + quad * 4 + r;
                    P[(((size_t)b * 16 + h) * 1024 + s) * 64 + e] =
                        __float2bfloat16(acc[mi][ni][r] * sc + bval);
                }
            }
        }
    }
}

// ---------------------------------------------------------------- QKV GEMM (fallback, raw X)
__global__ __launch_bounds__(256) void qkv_gemm2(
    const void* __restrict__ Xsrc,
    const __hip_bfloat16* __restrict__ WT,
    const __hip_bfloat16* __restrict__ bc,
    __hip_bfloat16* __restrict__ Q,
    __hip_bfloat16* __restrict__ Ko,
    __hip_bfloat16* __restrict__ Vt)
{
    __shared__ int s_is32;
    detect_mode((const unsigned*)Xsrc, &s_is32);
    __shared__ uint4 AsU[128 * 8];
    __shared__ uint4 BsU[128 * 8];
    int tid = threadIdx.x, lane = tid & 63, wave = tid >> 6;
    int quad = lane >> 4, ln = lane & 15;
    int m0 = blockIdx.x * 128;
    int n0 = blockIdx.y * 128;
    const __hip_bfloat16* Wp = WT + (size_t)n0 * 1024;
    const float* Xf = (const float*)Xsrc;
    const __hip_bfloat16* Xh = (const __hip_bfloat16*)Xsrc;

    floatx4 acc[2][8];
    #pragma unroll
    for (int i = 0; i < 2; i++)
        #pragma unroll
        for (int j = 0; j < 8; j++) acc[i][j] = (floatx4){0.f, 0.f, 0.f, 0.f};

    for (int k0 = 0; k0 < 1024; k0 += 64) {
        if (s_is32) {
            #pragma unroll
            for (int i = 0; i < 4; i++) {
                int id = tid + i * 256;
                int r = id >> 3, kc = id & 7;
                size_t off = (size_t)(m0 + r) * 1024 + k0 + kc * 8;
                float4 f0 = *(const float4*)(Xf + off);
                float4 f1 = *(const float4*)(Xf + off + 4);
                short8 s;
                s[0] = f2b(f0.x); s[1] = f2b(f0.y); s[2] = f2b(f0.z); s[3] = f2b(f0.w);
                s[4] = f2b(f1.x); s[5] = f2b(f1.y); s[6] = f2b(f1.z); s[7] = f2b(f1.w);
                AsU[swz(r, kc)] = __builtin_bit_cast(uint4, s);
            }
        } else {
            #pragma unroll
            for (int i = 0; i < 4; i++) {
                int id = tid + i * 256;
                int r = id >> 3, kc = id & 7;
                AsU[swz(r, kc)] = *(const uint4*)(Xh + (size_t)(m0 + r) * 1024 + k0 + kc * 8);
            }
        }
        #pragma unroll
        for (int i = 0; i < 4; i++) {
            int id = tid + i * 256;
            int r = id >> 3, kc = id & 7;
            BsU[swz(r, kc)] = *(const uint4*)(Wp + (size_t)r * 1024 + k0 + kc * 8);
        }
        __syncthreads();
        #pragma unroll
        for (int kk = 0; kk < 2; kk++) {
            short8 a0 = as_frag(AsU[swz(wave * 32 + ln, kk * 4 + quad)]);
            short8 a1 = as_frag(AsU[swz(wave * 32 + 16 + ln, kk * 4 + quad)]);
            #pragma unroll
            for (int nt = 0; nt < 8; nt++) {
                short8 bfr = as_frag(BsU[swz(nt * 16 + ln, kk * 4 + quad)]);
                acc[0][nt] = mfma16(a0, bfr, acc[0][nt]);
                acc[1][nt] = mfma16(a1, bfr, acc[1][nt]);
            }
        }
        __syncthreads();
    }

    int b = m0 >> 10;
    int s0 = m0 & 1023;
    #pragma unroll
    for (int nt = 0; nt < 8; nt++) {
        int n = n0 + nt * 16 + ln;
        int proj = n >> 10, h = (n >> 6) & 15, e = n & 63;
        float bval = __bfloat162float(bc[proj * 1024 + (n & 1023)]);
        float sc = (proj == 0) ? C2S : 1.f;
        #pragma unroll
        for (int mt = 0; mt < 2; mt++) {
            #pragma unroll
            for (int r = 0; r < 4; r++) {
                int s = s0 + wave * 32 + mt * 16 + quad * 4 + r;
                float v = acc[mt][nt][r] * sc + bval;
                if (proj == 2) {
                    Vt[(((size_t)b * 16 + h) * 64 + e) * 1024 + s] = __float2bfloat16(v);
                } else {
                    __hip_bfloat16* P = (proj == 0) ? Q : Ko;
                    P[(((size_t)b * 16 + h) * 1024 + s) * 64 + e] = __float2bfloat16(v);
                }
            }
        }
    }
}

// ---------------------------------------------------------------- attention
// grid (128, 4): x = bh (XCD-colocated), y = 256-row Q tile. 8 waves x 32 q-rows.
// Operand-swapped: S^T = K Q^T, O^T = V^T P^T. Q-frags direct from global (no Q LDS).
// KVBLK=128: stage K/V once per 128 t (sync; dma; sync), then 2 barrier-free
// sub-tile pipelines per stretch (P is per-wave). Q prescaled by C2S -> P = exp2(st).
// Mask loads for BOTH sub-tiles hoisted above the dma issue. LDS 64 KB -> 2 blocks/CU.
__global__ __launch_bounds__(512, 4) void attn(
    const __hip_bfloat16* __restrict__ Q,
    const __hip_bfloat16* __restrict__ K,
    const __hip_bfloat16* __restrict__ Vt,
    const unsigned long long* __restrict__ bits,  // [8][16 t][1024 q]
    __hip_bfloat16* __restrict__ ctx)             // [8][1024][1024]
{
    __shared__ uint4 KsU[2 * 512];                // 16 KB (2 sub-tiles of 64t x 64e)
    __shared__ uint4 VsU[2 * 512];                // 16 KB (2 sub-tiles of 64e x 64t)
    __shared__ uint4 PsU[8 * 256];                // 32 KB (8 waves x 32q x 8 chunks)

    int tid = threadIdx.x, lane = tid & 63, w = tid >> 6;   // w in {0..7}
    int quad = lane >> 4, ln = lane & 15;
    int bh = blockIdx.x;
    int q0 = blockIdx.y * 256;
    int b = bh >> 4, h = bh & 15;
    const __hip_bfloat16* Qp = Q + (size_t)bh * 1024 * 64;
    const __hip_bfloat16* Kp = K + (size_t)bh * 1024 * 64;
    const __hip_bfloat16* Vp = Vt + (size_t)bh * 64 * 1024;
    const unsigned long long* bp = bits + (size_t)b * 16 * 1024;

    short8 qf[2][2];
    #pragma unroll
    for (int g = 0; g < 2; g++)
        #pragma unroll
        for (int kk = 0; kk < 2; kk++)
            qf[g][kk] = as_frag(*(const uint4*)(
                Qp + (size_t)(q0 + w * 32 + g * 16 + ln) * 64 + kk * 32 + quad * 8));

    int r8 = lane >> 3;                 // 0..7  (== r&7 since w*8 ≡ 0 mod 8)
    int kc = (lane & 7) ^ r8;           // swizzled source chunk (loop-invariant)

    floatx4 acc_o[2][4];                          // [qg][e-tile]
    #pragma unroll
    for (int g = 0; g < 2; g++)
        #pragma unroll
        for (int i = 0; i < 4; i++) acc_o[g][i] = (floatx4){0.f, 0.f, 0.f, 0.f};
    float lsum[2] = {0.f, 0.f};
    __hip_bfloat16* Pw = (__hip_bfloat16*)&PsU[w * 256];

    for (int t0 = 0; t0 < 1024; t0 += 128) {
        __syncthreads();                          // prior-stretch K/V reads done
        int t64b = t0 >> 6;
        unsigned long long m00 = bp[((size_t)t64b << 10) + q0 + w * 32 + ln];
        unsigned long long m01 = bp[((size_t)t64b << 10) + q0 + w * 32 + 16 + ln];
        unsigned long long m10 = bp[((size_t)(t64b + 1) << 10) + q0 + w * 32 + ln];
        unsigned long long m11 = bp[((size_t)(t64b + 1) << 10) + q0 + w * 32 + 16 + ln];
        #pragma unroll
        for (int i = 0; i < 2; i++) {             // stage 2 sub-tiles (K and V)
            int tK = t0 + i * 64 + w * 8 + r8;
            dma16(Kp + (size_t)tK * 64 + kc * 8,
                  (char*)KsU + (size_t)(i * 512 + w * 64) * 16);
            int e = w * 8 + r8;
            dma16(Vp + (size_t)e * 1024 + t0 + i * 64 + kc * 8,
                  (char*)VsU + (size_t)(i * 512 + w * 64) * 16);
        }
        __syncthreads();                          // dma drained (vmcnt0 @ barrier)

        #pragma unroll
        for (int s = 0; s < 2; s++) {             // barrier-free: 2 sub-pipelines
            unsigned long long mcur0 = s ? m10 : m00;
            unsigned long long mcur1 = s ? m11 : m01;
            const uint4* Ks = KsU + s * 512;
            const uint4* Vs = VsU + s * 512;

            floatx4 st[2][4];
            #pragma unroll
            for (int g = 0; g < 2; g++)
                #pragma unroll
                for (int i = 0; i < 4; i++) st[g][i] = (floatx4){0.f, 0.f, 0.f, 0.f};
            __builtin_amdgcn_s_setprio(1);
            #pragma unroll
            for (int kk = 0; kk < 2; kk++) {
                #pragma unroll
                for (int tt = 0; tt < 4; tt++) {
                    short8 kf = as_frag(Ks[swz(tt * 16 + ln, kk * 4 + quad)]);
                    st[0][tt] = mfma16(kf, qf[0][kk], st[0][tt]);
                    st[1][tt] = mfma16(kf, qf[1][kk], st[1][tt]);
                }
            }
            __builtin_amdgcn_s_setprio(0);

            #pragma unroll
            for (int g = 0; g < 2; g++) {
                int qloc = g * 16 + ln;
                unsigned long long msh = (g ? mcur1 : mcur0) >> (quad * 4);
                #pragma unroll
                for (int tt = 0; tt < 4; tt++) {
                    unsigned mb = (unsigned)(msh >> (tt * 16)) & 0xFu;
                    float pe0 = (mb & 1u) ? 0.f : __builtin_amdgcn_exp2f(st[g][tt][0]);
                    float pe1 = (mb & 2u) ? 0.f : __builtin_amdgcn_exp2f(st[g][tt][1]);
                    float pe2 = (mb & 4u) ? 0.f : __builtin_amdgcn_exp2f(st[g][tt][2]);
                    float pe3 = (mb & 8u) ? 0.f : __builtin_amdgcn_exp2f(st[g][tt][3]);
                    lsum[g] += (pe0 + pe1) + (pe2 + pe3);
                    int kcp = tt * 2 + (quad >> 1);           // logical chunk of col
                    int off = qloc * 64 + (kcp ^ (qloc & 7)) * 8 + (quad & 1) * 4;
                    *(uint2*)(Pw + off) = pack4(pe0, pe1, pe2, pe3);
                }
            }

            __builtin_amdgcn_s_setprio(1);
            #pragma unroll
            for (int kk = 0; kk < 2; kk++) {
                short8 pf0 = as_frag(PsU[w * 256 + swz(0 * 16 + ln, kk * 4 + quad)]);
                short8 pf1 = as_frag(PsU[w * 256 + swz(1 * 16 + ln, kk * 4 + quad)]);
                #pragma unroll
                for (int et = 0; et < 4; et++) {
                    short8 vf = as_frag(Vs[swz(et * 16 + ln, kk * 4 + quad)]);
                    acc_o[0][et] = mfma16(vf, pf0, acc_o[0][et]);
                    acc_o[1][et] = mfma16(vf, pf1, acc_o[1][et]);
                }
            }
            __builtin_amdgcn_s_setprio(0);
        }
    }

    #pragma unroll
    for (int g = 0; g < 2; g++) {
        lsum[g] += __shfl_xor(lsum[g], 16, 64);
        lsum[g] += __shfl_xor(lsum[g], 32, 64);
    }

    #pragma unroll
    for (int g = 0; g < 2; g++) {
        float inv = 1.f / fmaxf(lsum[g], 1e-20f);
        int s = q0 + w * 32 + g * 16 + ln;
        __hip_bfloat16* crow = ctx + ((size_t)b * 1024 + s) * 1024 + h * 64 + quad * 4;
        #pragma unroll
        for (int et = 0; et < 4; et++) {
            uint2 pk = pack4(acc_o[g][et][0] * inv, acc_o[g][et][1] * inv,
                             acc_o[g][et][2] * inv, acc_o[g][et][3] * inv);
            *(uint2*)(crow + et * 16) = pk;
        }
    }
}

// ---------------------------------------------------------------- out GEMM (DMA)
// 128x128 tiles, grid (64,8) = 512 blocks = 2/CU; 2x2 waves (wave = 64m x 64n).
__global__ __launch_bounds__(256) void out_gemm_dma(
    const __hip_bfloat16* __restrict__ Cx,   // ctx [8192,1024]
    const __hip_bfloat16* __restrict__ WoT,  // [1024 n][1024 k]
    const __hip_bfloat16* __restrict__ bc,
    const unsigned* __restrict__ Xw,
    void* __restrict__ dout,
    int direct)
{
    __shared__ int s_is32;
    detect_mode(Xw, &s_is32);
    __shared__ uint4 AsU[128 * 8];
    __shared__ uint4 BsU[128 * 8];
    int tid = threadIdx.x, lane = tid & 63, wave = tid >> 6;
    int quad = lane >> 4, ln = lane & 15;
    int mw = wave & 1, nw = wave >> 1;
    int m0 = blockIdx.x * 128;
    int n0 = blockIdx.y * 128;

    floatx4 acc[4][4];
    #pragma unroll
    for (int i = 0; i < 4; i++)
        #pragma unroll
        for (int j = 0; j < 4; j++) acc[i][j] = (floatx4){0.f, 0.f, 0.f, 0.f};

    for (int k0 = 0; k0 < 1024; k0 += 64) {
        #pragma unroll
        for (int i = 0; i < 4; i++) {
            int r = wave * 32 + i * 8 + (lane >> 3);
            int kc = (lane & 7) ^ (r & 7);
            char* ldsA = (char*)AsU + (size_t)(wave * 256 + i * 64) * 16;
            char* ldsB = (char*)BsU + (size_t)(wave * 256 + i * 64) * 16;
            dma16(Cx + (size_t)(m0 + r) * 1024 + k0 + kc * 8, ldsA);
            dma16(WoT + (size_t)(n0 + r) * 1024 + k0 + kc * 8, ldsB);
        }
        __syncthreads();
        #pragma unroll
        for (int kk = 0; kk < 2; kk++) {
            short8 af[4], bfr[4];
            #pragma unroll
            for (int mi = 0; mi < 4; mi++)
                af[mi] = as_frag(AsU[swz(mw * 64 + mi * 16 + ln, kk * 4 + quad)]);
            #pragma unroll
            for (int ni = 0; ni < 4; ni++)
                bfr[ni] = as_frag(BsU[swz(nw * 64 + ni * 16 + ln, kk * 4 + quad)]);
            #pragma unroll
            for (int mi = 0; mi < 4; mi++)
                #pragma unroll
                for (int ni = 0; ni < 4; ni++)
                    acc[mi][ni] = mfma16(af[mi], bfr[ni], acc[mi][ni]);
        }
        __syncthreads();
    }

    const __hip_bfloat16* bo = bc + 3 * 1024;
    #pragma unroll
    for (int ni = 0; ni < 4; ni++) {
        int n = n0 + nw * 64 + ni * 16 + ln;
        float bval = __bfloat162float(bo[n]);
        #pragma unroll
        for (int mi = 0; mi < 4; mi++) {
            #pragma unroll
            for (int r = 0; r < 4; r++) {
                int m = m0 + mw * 64 + mi * 16 + quad * 4 + r;
                float v = acc[mi][ni][r] + bval;
                if (direct && s_is32) ((float*)dout)[(size_t)m * 1024 + n] = v;
                else ((__hip_bfloat16*)dout)[(size_t)m * 1024 + n] = __float2bfloat16(v);
            }
        }
    }
}

// ---------------------------------------------------------------- emit (fallback)
__global__ __launch_bounds__(256) void emit_out(
    const __hip_bfloat16* __restrict__ Fo, const unsigned* __restrict__ Xw,
    void* __restrict__ dout)
{
    __shared__ int s_is32;
    detect_mode(Xw, &s_is32);
    size_t g = (size_t)blockIdx.x * 256 + threadIdx.x;
    uint4 u = *(const uint4*)(Fo + g * 8);
    if (s_is32) {
        short8 s = __builtin_bit_cast(short8, u);
        float4 f0, f1;
        f0.x = b2f(s[0]); f0.y = b2f(s[1]); f0.z = b2f(s[2]); f0.w = b2f(s[3]);
        f1.x = b2f(s[4]); f1.y = b2f(s[5]); f1.z = b2f(s[6]); f1.w = b2f(s[7]);
        *(float4*)((float*)dout + g * 8) = f0;
        *(float4*)((float*)dout + g * 8 + 4) = f1;
    } else {
        *(uint4*)((__hip_bfloat16*)dout + g * 8) = u;
    }
}

// ---------------------------------------------------------------- launch
extern "C" void kernel_launch(void* const* d_in, const int* in_sizes, int n_in,
                              void* d_out, int out_size, void* d_ws, size_t ws_size,
                              hipStream_t stream) {
    const void* X  = d_in[0];
    const void* mk = d_in[1];
    const void* Wq = d_in[2];
    const void* bq = d_in[3];
    const void* Wk = d_in[4];
    const void* bk = d_in[5];
    const void* Wv = d_in[6];
    const void* bv = d_in[7];
    const void* Wo = d_in[8];
    const void* bo = d_in[9];
    const unsigned* Xw = (const unsigned*)X;

    char* ws = (char*)d_ws;
    __hip_bfloat16*     WT   = (__hip_bfloat16*)(ws);                        // [0, 6 MB)
    __hip_bfloat16*     WoT  = (__hip_bfloat16*)(ws + ((size_t)6 << 20));    // [6, 8 MB)
    unsigned long long* bits = (unsigned long long*)(ws + ((size_t)8 << 20));// [8, 9 MB)
    __hip_bfloat16*     bc   = (__hip_bfloat16*)(ws + ((size_t)9 << 20));    // [9, +8KB)
    __hip_bfloat16*     Xb   = (__hip_bfloat16*)(ws + ((size_t)10 << 20));   // [10, 26 MB)
    __hip_bfloat16*     Qb   = (__hip_bfloat16*)(ws + ((size_t)26 << 20));   // [26, 42 MB)
    __hip_bfloat16*     Kb   = (__hip_bfloat16*)(ws + ((size_t)42 << 20));   // [42, 58 MB)
    __hip_bfloat16*     Vtb  = (__hip_bfloat16*)(ws + ((size_t)58 << 20));   // [58, 74 MB)

    bool bigws = ws_size >= ((size_t)74 << 20);

    hipLaunchKernelGGL(prep_all, dim3(4609), dim3(256), 0, stream,
                       Wq, Wk, Wv, Wo, bq, bk, bv, bo, mk, X,
                       WT, WoT, bc, bits, Xb, bigws ? 1 : 0);

    if (bigws) {
        __hip_bfloat16* Cx = Xb;   // ctx reuses Xb (dead after qkv)
        hipLaunchKernelGGL(qkv_gemm_dma, dim3(32, 12), dim3(512), 0, stream,
                           Xb, WT, bc, Qb, Kb, Vtb);
        hipLaunchKernelGGL(attn, dim3(128, 4), dim3(512), 0, stream,
                           Qb, Kb, Vtb, bits, Cx);
        hipLaunchKernelGGL(out_gemm_dma, dim3(64, 8), dim3(256), 0, stream,
                           Cx, WoT, bc, Xw, d_out, 1);
    } else {
        __hip_bfloat16* Cx = (__hip_bfloat16*)d_out;   // ctx scratch in d_out
        __hip_bfloat16* Fo = Qb;                        // final bf16 over dead Q
        hipLaunchKernelGGL(qkv_gemm2, dim3(64, 24), dim3(256), 0, stream,
                           X, WT, bc, Qb, Kb, Vtb);
        hipLaunchKernelGGL(attn, dim3(128, 4), dim3(512), 0, stream,
                           Qb, Kb, Vtb, bits, Cx);
        hipLaunchKernelGGL(out_gemm_dma, dim3(64, 8), dim3(256), 0, stream,
                           Cx, WoT, bc, Xw, (void*)Fo, 0);
        hipLaunchKernelGGL(emit_out, dim3(4096), dim3(256), 0, stream,
                           Fo, Xw, d_out);
    }
}

// Round 10
// 299.161 us; speedup vs baseline: 1.0155x; 1.0155x over previous
//
#include <hip/hip_runtime.h>
#include <hip/hip_bf16.h>
#include <stdint.h>

// MultiHeadAttention: B=8, S=1024, D=1024, H=16, DH=64. fp32 in/out (auto-detects bf16).
// Round-18: fix r17's bank-conflict bug in the 8-phase qkv. With BK=64 a row is
// 64B (4 slots): bank pattern period = 2 rows, old XOR (row&3) period 4 -> 4-way
// conflict (4.7M counted, 1.58x LDS path). New g(row) = (row>>1)&3 cycles all 4
// slots across equal-parity rows -> exact 2-way (free). Read rslot = quad^((ln>>1)&3),
// staging source chunk kcS = (lane&3)^((lane>>3)&3). Same involution both sides;
// schedule/vmcnt/barriers identical to r17 (correctness already verified).
// attn/prep/out unchanged from r16 best: attn de-lockstep 8w x 32q, prep mask-pack
// 1536 blocks, out 128^2 grid(64,8).
// ws layout A (>=74MB): WT@0(6) WoT@6(2) bits@8(1) bc@9 Xb@10(16,reused as ctx) Q@26 K@42 Vt@58
// ws layout B (<74MB):  raw-X fallback gemm; ctx in d_out; emit kernel.

typedef __attribute__((ext_vector_type(8))) short short8;
typedef __attribute__((ext_vector_type(4))) float floatx4;

#define C2S 0.04508422f   // (1/sqrt(1024)) * log2(e), folded into Q

__device__ __forceinline__ int swz(int r, int kc) { return r * 8 + (kc ^ (r & 7)); }
__device__ __forceinline__ short8 as_frag(uint4 u) { return __builtin_bit_cast(short8, u); }
__device__ __forceinline__ floatx4 mfma16(short8 a, short8 b, floatx4 c) {
    return __builtin_amdgcn_mfma_f32_16x16x32_bf16(a, b, c, 0, 0, 0);
}
__device__ __forceinline__ unsigned short f2bu(float f) {
    return __builtin_bit_cast(unsigned short, __float2bfloat16(f));
}
__device__ __forceinline__ short f2b(float f) {
    return __builtin_bit_cast(short, __float2bfloat16(f));
}
__device__ __forceinline__ float b2f(short s) {
    return __bfloat162float(__builtin_bit_cast(__hip_bfloat16, s));
}
// async global->LDS DMA, 16B per lane; lds dest = wave-uniform base + lane*16
__device__ __forceinline__ void dma16(const void* g, void* l) {
    __builtin_amdgcn_global_load_lds(
        (const __attribute__((address_space(1))) uint32_t*)g,
        (__attribute__((address_space(3))) uint32_t*)l, 16, 0, 0);
}
__device__ __forceinline__ uint2 pack4(float a, float b, float c, float d) {
    uint2 p;
    p.x = (unsigned)f2bu(a) | ((unsigned)f2bu(b) << 16);
    p.y = (unsigned)f2bu(c) | ((unsigned)f2bu(d) << 16);
    return p;
}

// Runtime dtype detection: bf16 data has sane exponents in the LOW halves of
// 32-bit words; fp32 data has uniform mantissa bits there.
__device__ __forceinline__ void detect_mode(const unsigned* Xw, int* s_is32) {
    if (threadIdx.x < 64) {
        unsigned lo = Xw[threadIdx.x] & 0xFFFFu;
        unsigned e = (lo >> 7) & 0xFFu;
        unsigned long long bal = __ballot(e >= 88u && e <= 150u);
        if (threadIdx.x == 0) *s_is32 = (bal != ~0ull) ? 1 : 0;
    }
    __syncthreads();
}

__device__ __forceinline__ float load_elt(const void* p, size_t idx, int is32) {
    return is32 ? ((const float*)p)[idx]
                : __bfloat162float(((const __hip_bfloat16*)p)[idx]);
}

// ---------------------------------------------------------------- fused prep
// blocks [0,1024): weight transpose (vectorized); [1024]: biases;
// [1025,2561): mask pack (t-major, 1536 blocks); [2561,4609): X convert.
__global__ __launch_bounds__(256) void prep_all(
    const void* __restrict__ Wq, const void* __restrict__ Wk,
    const void* __restrict__ Wv, const void* __restrict__ Wo,
    const void* __restrict__ bq, const void* __restrict__ bk,
    const void* __restrict__ bv, const void* __restrict__ bo,
    const void* __restrict__ mask_raw, const void* __restrict__ X,
    __hip_bfloat16* __restrict__ WT, __hip_bfloat16* __restrict__ WoT,
    __hip_bfloat16* __restrict__ bc, unsigned long long* __restrict__ bits64,
    __hip_bfloat16* __restrict__ Xb, int do_x)
{
    __shared__ __hip_bfloat16 T[64][72];
    __shared__ int s_is32;
    int blk = blockIdx.x;
    int tid = threadIdx.x;
    const unsigned* Xw = (const unsigned*)X;

    if (blk < 1024) {                           // ---- weight transpose (vectorized)
        detect_mode(Xw, &s_is32);
        const void* src; size_t src_off;
        __hip_bfloat16* dst;
        int src_ld, dst_ld;
        if (blk < 768) {                        // Wq/Wk/Wv: [h][d][e] -> WT[(p,h,e)][d]
            int p = blk >> 8;
            int rem = blk & 255;
            int h = rem >> 4, dt = rem & 15;
            src = (p == 0) ? Wq : (p == 1) ? Wk : Wv;
            src_off = ((size_t)h * 1024 + (size_t)dt * 64) * 64;
            dst = WT + (((size_t)p * 16 + h) * 64) * 1024 + dt * 64;
            src_ld = 64; dst_ld = 1024;
        } else {                                // Wo: [k][n] -> WoT[n][k]
            int t = blk - 768;
            int kt = t >> 4, nt = t & 15;
            src = Wo; src_off = (size_t)kt * 64 * 1024 + nt * 64;
            dst = WoT + (size_t)nt * 64 * 1024 + kt * 64;
            src_ld = 1024; dst_ld = 1024;
        }
        #pragma unroll
        for (int i = 0; i < 2; i++) {
            int seg = tid + i * 256;
            int r = seg >> 3, c0 = (seg & 7) * 8;
            if (s_is32) {
                const float* sf = (const float*)src + src_off + (size_t)r * src_ld + c0;
                float4 f0 = *(const float4*)sf;
                float4 f1 = *(const float4*)(sf + 4);
                T[c0 + 0][r] = __float2bfloat16(f0.x);
                T[c0 + 1][r] = __float2bfloat16(f0.y);
                T[c0 + 2][r] = __float2bfloat16(f0.z);
                T[c0 + 3][r] = __float2bfloat16(f0.w);
                T[c0 + 4][r] = __float2bfloat16(f1.x);
                T[c0 + 5][r] = __float2bfloat16(f1.y);
                T[c0 + 6][r] = __float2bfloat16(f1.z);
                T[c0 + 7][r] = __float2bfloat16(f1.w);
            } else {
                const __hip_bfloat16* sh =
                    (const __hip_bfloat16*)src + src_off + (size_t)r * src_ld + c0;
                uint4 u = *(const uint4*)sh;
                short8 s8 = __builtin_bit_cast(short8, u);
                #pragma unroll
                for (int j = 0; j < 8; j++)
                    T[c0 + j][r] = __builtin_bit_cast(__hip_bfloat16, (short)s8[j]);
            }
        }
        __syncthreads();
        #pragma unroll
        for (int i = 0; i < 2; i++) {
            int seg = tid + i * 256;
            int r = seg >> 3, c0 = (seg & 7) * 8;
            *(uint4*)(dst + (size_t)r * dst_ld + c0) = *(const uint4*)(&T[r][c0]);
        }
    } else if (blk == 1024) {                   // ---- biases (bq prescaled by C2S)
        detect_mode(Xw, &s_is32);
        #pragma unroll
        for (int i = 0; i < 16; i++) {
            int idx = tid + i * 256;
            int which = idx >> 10, j = idx & 1023;
            const void* src = (which == 0) ? bq : (which == 1) ? bk : (which == 2) ? bv : bo;
            float v = load_elt(src, j, s_is32);
            if (which == 0) v *= C2S;
            bc[idx] = __float2bfloat16(v);
        }
    } else if (blk < 2561) {                    // ---- mask pack (1536 blocks), t-major out
        int blkL = blk - 1025;
        const int* mi = (const int*)mask_raw;
        const unsigned char* mb = (const unsigned char*)mask_raw;
        int lane = tid & 63;
        bool ok = true;
        #pragma unroll
        for (int i = 0; i < 4; i++) {
            unsigned v = (unsigned)mi[lane * 4 + i];
            if (v > 1u) ok = false;
        }
        bool is_i32 = (__ballot(ok) == ~0ull);
        int gw = (blkL * 256 + tid) >> 6;
        const int NW = 1536 * 4;
        const int NWORDS = (8 * 1024 * 1024) / 64;
        // src word i = (b*1024 + q)*16 + t  ->  dst (b*16 + t)*1024 + q
        if (is_i32) {
            for (int i = gw; i < NWORDS; i += NW) {
                int mv = mi[(size_t)i * 64 + lane];
                unsigned long long bal = __ballot(mv != 0);
                if (lane == 0) {
                    int bb = i >> 14, q = (i >> 4) & 1023, t = i & 15;
                    bits64[((size_t)bb << 14) + ((size_t)t << 10) + q] = bal;
                }
            }
        } else {
            for (int i = gw; i < NWORDS; i += NW) {
                int mv = mb[(size_t)i * 64 + lane];
                unsigned long long bal = __ballot(mv != 0);
                if (lane == 0) {
                    int bb = i >> 14, q = (i >> 4) & 1023, t = i & 15;
                    bits64[((size_t)bb << 14) + ((size_t)t << 10) + q] = bal;
                }
            }
        }
    } else if (do_x) {                          // ---- X convert (2048 blocks)
        detect_mode(Xw, &s_is32);
        int blkL = blk - 2561;
        size_t g = ((size_t)blkL * 256 + tid) * 16;
        if (s_is32) {
            const float* Xf = (const float*)X;
            #pragma unroll
            for (int half = 0; half < 2; half++) {
                float4 f0 = *(const float4*)(Xf + g + half * 8);
                float4 f1 = *(const float4*)(Xf + g + half * 8 + 4);
                short8 s;
                s[0] = f2b(f0.x); s[1] = f2b(f0.y); s[2] = f2b(f0.z); s[3] = f2b(f0.w);
                s[4] = f2b(f1.x); s[5] = f2b(f1.y); s[6] = f2b(f1.z); s[7] = f2b(f1.w);
                *(uint4*)(Xb + g + half * 8) = __builtin_bit_cast(uint4, s);
            }
        } else {
            const uint4* Xu = (const uint4*)X;
            *(uint4*)(Xb + g)     = Xu[g / 8];
            *(uint4*)(Xb + g + 8) = Xu[g / 8 + 1];
        }
    }
}

// ---------------------------------------------------------------- QKV GEMM (8-phase)
// C[8192 m, 3072 n] = Xb @ WT^T. 256x256 tiles, BK=64, grid (32 m, 12 n), 8 waves.
// LDS layout: [buf*2+kh][row][slot], slot = chunk ^ g(row), g(row) = (row>>1)&3
// (2-way bank aliasing = free; r17's (row&3) was 4-way). chunk = 8 bf16 = 16B.
// Phase = (kk, mihalf): 16 MFMA; B-frags loaded at mihalf 0, carried to mihalf 1.
// Staging: 1 khalf-tile (2 dma16/wave) per phase, earliest-safe placement;
// vmcnt(6) at ph4/ph8 (counted, never drains); proj-0 scaled by C2S.
#define VM6 asm volatile("s_waitcnt vmcnt(6)" ::: "memory")
#define VM0 asm volatile("s_waitcnt vmcnt(0)" ::: "memory")
#define FENCE asm volatile("" ::: "memory")

#define QPH(BUF, KK, MH, LOADB, STAGE_STMT, WAIT_STMT)                          \
  {                                                                             \
    const int base_ = ((BUF) * 2 + (KK)) * 1024;                                \
    short8 af0 = as_frag(AsU[base_ + (mw * 128 + ((MH) * 4 + 0) * 16 + ln) * 4 + rslot]); \
    short8 af1 = as_frag(AsU[base_ + (mw * 128 + ((MH) * 4 + 1) * 16 + ln) * 4 + rslot]); \
    short8 af2 = as_frag(AsU[base_ + (mw * 128 + ((MH) * 4 + 2) * 16 + ln) * 4 + rslot]); \
    short8 af3 = as_frag(AsU[base_ + (mw * 128 + ((MH) * 4 + 3) * 16 + ln) * 4 + rslot]); \
    if (LOADB) {                                                                \
      bf[0] = as_frag(BsU[base_ + (nw * 64 + 0 * 16 + ln) * 4 + rslot]);        \
      bf[1] = as_frag(BsU[base_ + (nw * 64 + 1 * 16 + ln) * 4 + rslot]);        \
      bf[2] = as_frag(BsU[base_ + (nw * 64 + 2 * 16 + ln) * 4 + rslot]);        \
      bf[3] = as_frag(BsU[base_ + (nw * 64 + 3 * 16 + ln) * 4 + rslot]);        \
    }                                                                           \
    STAGE_STMT;                                                                 \
    FENCE; __builtin_amdgcn_s_barrier(); FENCE;                                 \
    __builtin_amdgcn_s_setprio(1);                                              \
    acc[(MH) * 4 + 0][0] = mfma16(af0, bf[0], acc[(MH) * 4 + 0][0]);            \
    acc[(MH) * 4 + 0][1] = mfma16(af0, bf[1], acc[(MH) * 4 + 0][1]);            \
    acc[(MH) * 4 + 0][2] = mfma16(af0, bf[2], acc[(MH) * 4 + 0][2]);            \
    acc[(MH) * 4 + 0][3] = mfma16(af0, bf[3], acc[(MH) * 4 + 0][3]);            \
    acc[(MH) * 4 + 1][0] = mfma16(af1, bf[0], acc[(MH) * 4 + 1][0]);            \
    acc[(MH) * 4 + 1][1] = mfma16(af1, bf[1], acc[(MH) * 4 + 1][1]);            \
    acc[(MH) * 4 + 1][2] = mfma16(af1, bf[2], acc[(MH) * 4 + 1][2]);            \
    acc[(MH) * 4 + 1][3] = mfma16(af1, bf[3], acc[(MH) * 4 + 1][3]);            \
    acc[(MH) * 4 + 2][0] = mfma16(af2, bf[0], acc[(MH) * 4 + 2][0]);            \
    acc[(MH) * 4 + 2][1] = mfma16(af2, bf[1], acc[(MH) * 4 + 2][1]);            \
    acc[(MH) * 4 + 2][2] = mfma16(af2, bf[2], acc[(MH) * 4 + 2][2]);            \
    acc[(MH) * 4 + 2][3] = mfma16(af2, bf[3], acc[(MH) * 4 + 2][3]);            \
    acc[(MH) * 4 + 3][0] = mfma16(af3, bf[0], acc[(MH) * 4 + 3][0]);            \
    acc[(MH) * 4 + 3][1] = mfma16(af3, bf[1], acc[(MH) * 4 + 3][1]);            \
    acc[(MH) * 4 + 3][2] = mfma16(af3, bf[2], acc[(MH) * 4 + 3][2]);            \
    acc[(MH) * 4 + 3][3] = mfma16(af3, bf[3], acc[(MH) * 4 + 3][3]);            \
    __builtin_amdgcn_s_setprio(0);                                              \
    WAIT_STMT;                                                                  \
    FENCE; __builtin_amdgcn_s_barrier(); FENCE;                                 \
  }

__global__ __launch_bounds__(512, 2) void qkv_gemm_dma(
    const __hip_bfloat16* __restrict__ Xb,   // [8192][1024] bf16
    const __hip_bfloat16* __restrict__ WT,   // [3072 n][1024 k]
    const __hip_bfloat16* __restrict__ bc,   // [4][1024]
    __hip_bfloat16* __restrict__ Q,
    __hip_bfloat16* __restrict__ Ko,
    __hip_bfloat16* __restrict__ Vt)
{
    __shared__ uint4 AsU[4096];   // 64 KB: [buf*2+kh][256 rows][4 slots]
    __shared__ uint4 BsU[4096];   // 64 KB
    int tid = threadIdx.x, lane = tid & 63, w = tid >> 6;   // 8 waves
    int quad = lane >> 4, ln = lane & 15;
    int mw = w & 1, nw = w >> 1;                            // 2M x 4N
    int m0 = blockIdx.x * 256;
    int n0 = blockIdx.y * 256;
    const __hip_bfloat16* Wp = WT + (size_t)n0 * 1024;

    // staging geometry: issue j covers rows (w*2+j)*16 + (lane>>2), slot lane&3;
    // source chunk pre-swizzled: kcS = (lane&3) ^ g(row), g(row) = (row>>1)&3
    // = ((lane>>2)>>1)&3 = (lane>>3)&3  (row base multiple of 16).
    int l2 = lane >> 2;
    int kcS = (lane & 3) ^ ((lane >> 3) & 3);
    // frag-read slot: g(row) = (ln>>1)&3 (row base multiple of 16)
    int rslot = quad ^ ((ln >> 1) & 3);

    floatx4 acc[8][4];
    #pragma unroll
    for (int i = 0; i < 8; i++)
        #pragma unroll
        for (int j = 0; j < 4; j++) acc[i][j] = (floatx4){0.f, 0.f, 0.f, 0.f};

    auto stA = [&](int kt, int kh) {
        int kh2 = (kt & 1) * 2 + kh;
        #pragma unroll
        for (int j = 0; j < 2; j++) {
            int r = (w * 2 + j) * 16 + l2;
            dma16(Xb + (size_t)(m0 + r) * 1024 + kt * 64 + kh * 32 + kcS * 8,
                  (char*)AsU + (size_t)(kh2 * 1024 + (w * 2 + j) * 64) * 16);
        }
    };
    auto stB = [&](int kt, int kh) {
        int kh2 = (kt & 1) * 2 + kh;
        #pragma unroll
        for (int j = 0; j < 2; j++) {
            int r = (w * 2 + j) * 16 + l2;
            dma16(Wp + (size_t)r * 1024 + kt * 64 + kh * 32 + kcS * 8,
                  (char*)BsU + (size_t)(kh2 * 1024 + (w * 2 + j) * 64) * 16);
        }
    };

    // prologue: tile0 fully + tile1's first 3 khalf-tiles (A(1)kh1 staged in ph1)
    stB(0, 0); stA(0, 0); stB(0, 1); stA(0, 1);
    stB(1, 0); stA(1, 0); stB(1, 1);
    VM6;                          // tile0's 4 half-tiles landed (last 3 may fly)
    FENCE; __builtin_amdgcn_s_barrier(); FENCE;

    short8 bf[4];
    for (int it = 0; it < 8; it++) {
        int T = 2 * it;
        bool more = (it < 7);
        QPH(0, 0, 0, 1, { stA(T + 1, 1); },              {})                  // ph1
        QPH(0, 0, 1, 0, { if (more) stB(T + 2, 0); },    {})                  // ph2
        QPH(0, 1, 0, 1, { if (more) stA(T + 2, 0); },    {})                  // ph3
        QPH(0, 1, 1, 0, { if (more) stB(T + 2, 1); },
            { if (more) { VM6; } else { VM0; } })                             // ph4
        QPH(1, 0, 0, 1, { if (more) stA(T + 2, 1); },    {})                  // ph5
        QPH(1, 0, 1, 0, { if (more) stB(T + 3, 0); },    {})                  // ph6
        QPH(1, 1, 0, 1, { if (more) stA(T + 3, 0); },    {})                  // ph7
        QPH(1, 1, 1, 0, { if (more) stB(T + 3, 1); },
            { if (more) { VM6; } })                                           // ph8
    }

    int b = m0 >> 10;
    int s0 = m0 & 1023;
    int proj = n0 >> 10;                     // uniform per block (256 | 1024)
    if (proj == 2) {
        #pragma unroll
        for (int ni = 0; ni < 4; ni++) {
            int n = n0 + nw * 64 + ni * 16 + ln;
            int h = (n >> 6) & 15, e = n & 63;
            float bval = __bfloat162float(bc[2 * 1024 + (n & 1023)]);
            #pragma unroll
            for (int mi = 0; mi < 8; mi++) {
                int sb = s0 + mw * 128 + mi * 16 + quad * 4;
                uint2 pk = pack4(acc[mi][ni][0] + bval, acc[mi][ni][1] + bval,
                                 acc[mi][ni][2] + bval, acc[mi][ni][3] + bval);
                *(uint2*)(Vt + (((size_t)b * 16 + h) * 64 + e) * 1024 + sb) = pk;
            }
        }
    } else {
        __hip_bfloat16* P = (proj == 0) ? Q : Ko;
        float sc = (proj == 0) ? C2S : 1.f;   // fold attn scale*log2e into Q
        #pragma unroll
        for (int ni = 0; ni < 4; ni++) {
            int n = n0 + nw * 64 + ni * 16 + ln;
            int h = (n >> 6) & 15, e = n & 63;
            float bval = __bfloat162float(bc[proj * 1024 + (n & 1023)]);
            #pragma unroll
            for (int mi = 0; mi < 8; mi++) {
                #pragma unroll
                for (int r = 0; r < 4; r++) {
                    int s = s0 + mw * 128 + mi * 16 + quad * 4 + r;
                    P[(((size_t)b * 16 + h) * 1024 + s) * 64 + e] =
                        __float2bfloat16(acc[mi][ni][r] * sc + bval);
                }
            }
        }
    }
}

// ---------------------------------------------------------------- QKV GEMM (fallback, raw X)
__global__ __launch_bounds__(256) void qkv_gemm2(
    const void* __restrict__ Xsrc,
    const __hip_bfloat16* __restrict__ WT,
    const __hip_bfloat16* __restrict__ bc,
    __hip_bfloat16* __restrict__ Q,
    __hip_bfloat16* __restrict__ Ko,
    __hip_bfloat16* __restrict__ Vt)
{
    __shared__ int s_is32;
    detect_mode((const unsigned*)Xsrc, &s_is32);
    __shared__ uint4 AsU[128 * 8];
    __shared__ uint4 BsU[128 * 8];
    int tid = threadIdx.x, lane = tid & 63, wave = tid >> 6;
    int quad = lane >> 4, ln = lane & 15;
    int m0 = blockIdx.x * 128;
    int n0 = blockIdx.y * 128;
    const __hip_bfloat16* Wp = WT + (size_t)n0 * 1024;
    const float* Xf = (const float*)Xsrc;
    const __hip_bfloat16* Xh = (const __hip_bfloat16*)Xsrc;

    floatx4 acc[2][8];
    #pragma unroll
    for (int i = 0; i < 2; i++)
        #pragma unroll
        for (int j = 0; j < 8; j++) acc[i][j] = (floatx4){0.f, 0.f, 0.f, 0.f};

    for (int k0 = 0; k0 < 1024; k0 += 64) {
        if (s_is32) {
            #pragma unroll
            for (int i = 0; i < 4; i++) {
                int id = tid + i * 256;
                int r = id >> 3, kc = id & 7;
                size_t off = (size_t)(m0 + r) * 1024 + k0 + kc * 8;
                float4 f0 = *(const float4*)(Xf + off);
                float4 f1 = *(const float4*)(Xf + off + 4);
                short8 s;
                s[0] = f2b(f0.x); s[1] = f2b(f0.y); s[2] = f2b(f0.z); s[3] = f2b(f0.w);
                s[4] = f2b(f1.x); s[5] = f2b(f1.y); s[6] = f2b(f1.z); s[7] = f2b(f1.w);
                AsU[swz(r, kc)] = __builtin_bit_cast(uint4, s);
            }
        } else {
            #pragma unroll
            for (int i = 0; i < 4; i++) {
                int id = tid + i * 256;
                int r = id >> 3, kc = id & 7;
                AsU[swz(r, kc)] = *(const uint4*)(Xh + (size_t)(m0 + r) * 1024 + k0 + kc * 8);
            }
        }
        #pragma unroll
        for (int i = 0; i < 4; i++) {
            int id = tid + i * 256;
            int r = id >> 3, kc = id & 7;
            BsU[swz(r, kc)] = *(const uint4*)(Wp + (size_t)r * 1024 + k0 + kc * 8);
        }
        __syncthreads();
        #pragma unroll
        for (int kk = 0; kk < 2; kk++) {
            short8 a0 = as_frag(AsU[swz(wave * 32 + ln, kk * 4 + quad)]);
            short8 a1 = as_frag(AsU[swz(wave * 32 + 16 + ln, kk * 4 + quad)]);
            #pragma unroll
            for (int nt = 0; nt < 8; nt++) {
                short8 bfr = as_frag(BsU[swz(nt * 16 + ln, kk * 4 + quad)]);
                acc[0][nt] = mfma16(a0, bfr, acc[0][nt]);
                acc[1][nt] = mfma16(a1, bfr, acc[1][nt]);
            }
        }
        __syncthreads();
    }

    int b = m0 >> 10;
    int s0 = m0 & 1023;
    #pragma unroll
    for (int nt = 0; nt < 8; nt++) {
        int n = n0 + nt * 16 + ln;
        int proj = n >> 10, h = (n >> 6) & 15, e = n & 63;
        float bval = __bfloat162float(bc[proj * 1024 + (n & 1023)]);
        float sc = (proj == 0) ? C2S : 1.f;
        #pragma unroll
        for (int mt = 0; mt < 2; mt++) {
            #pragma unroll
            for (int r = 0; r < 4; r++) {
                int s = s0 + wave * 32 + mt * 16 + quad * 4 + r;
                float v = acc[mt][nt][r] * sc + bval;
                if (proj == 2) {
                    Vt[(((size_t)b * 16 + h) * 64 + e) * 1024 + s] = __float2bfloat16(v);
                } else {
                    __hip_bfloat16* P = (proj == 0) ? Q : Ko;
                    P[(((size_t)b * 16 + h) * 1024 + s) * 64 + e] = __float2bfloat16(v);
                }
            }
        }
    }
}

// ---------------------------------------------------------------- attention
// grid (128, 4): x = bh (XCD-colocated), y = 256-row Q tile. 8 waves x 32 q-rows.
// Operand-swapped: S^T = K Q^T, O^T = V^T P^T. Q-frags direct from global (no Q LDS).
// KVBLK=128: stage K/V once per 128 t (sync; dma; sync), then 2 barrier-free
// sub-tile pipelines per stretch (P is per-wave). Q prescaled by C2S -> P = exp2(st).
// Mask loads for BOTH sub-tiles hoisted above the dma issue. LDS 64 KB -> 2 blocks/CU.
__global__ __launch_bounds__(512, 4) void attn(
    const __hip_bfloat16* __restrict__ Q,
    const __hip_bfloat16* __restrict__ K,
    const __hip_bfloat16* __restrict__ Vt,
    const unsigned long long* __restrict__ bits,  // [8][16 t][1024 q]
    __hip_bfloat16* __restrict__ ctx)             // [8][1024][1024]
{
    __shared__ uint4 KsU[2 * 512];                // 16 KB (2 sub-tiles of 64t x 64e)
    __shared__ uint4 VsU[2 * 512];                // 16 KB (2 sub-tiles of 64e x 64t)
    __shared__ uint4 PsU[8 * 256];                // 32 KB (8 waves x 32q x 8 chunks)

    int tid = threadIdx.x, lane = tid & 63, w = tid >> 6;   // w in {0..7}
    int quad = lane >> 4, ln = lane & 15;
    int bh = blockIdx.x;
    int q0 = blockIdx.y * 256;
    int b = bh >> 4, h = bh & 15;
    const __hip_bfloat16* Qp = Q + (size_t)bh * 1024 * 64;
    const __hip_bfloat16* Kp = K + (size_t)bh * 1024 * 64;
    const __hip_bfloat16* Vp = Vt + (size_t)bh * 64 * 1024;
    const unsigned long long* bp = bits + (size_t)b * 16 * 1024;

    short8 qf[2][2];
    #pragma unroll
    for (int g = 0; g < 2; g++)
        #pragma unroll
        for (int kk = 0; kk < 2; kk++)
            qf[g][kk] = as_frag(*(const uint4*)(
                Qp + (size_t)(q0 + w * 32 + g * 16 + ln) * 64 + kk * 32 + quad * 8));

    int r8 = lane >> 3;                 // 0..7  (== r&7 since w*8 ≡ 0 mod 8)
    int kc = (lane & 7) ^ r8;           // swizzled source chunk (loop-invariant)

    floatx4 acc_o[2][4];                          // [qg][e-tile]
    #pragma unroll
    for (int g = 0; g < 2; g++)
        #pragma unroll
        for (int i = 0; i < 4; i++) acc_o[g][i] = (floatx4){0.f, 0.f, 0.f, 0.f};
    float lsum[2] = {0.f, 0.f};
    __hip_bfloat16* Pw = (__hip_bfloat16*)&PsU[w * 256];

    for (int t0 = 0; t0 < 1024; t0 += 128) {
        __syncthreads();                          // prior-stretch K/V reads done
        int t64b = t0 >> 6;
        unsigned long long m00 = bp[((size_t)t64b << 10) + q0 + w * 32 + ln];
        unsigned long long m01 = bp[((size_t)t64b << 10) + q0 + w * 32 + 16 + ln];
        unsigned long long m10 = bp[((size_t)(t64b + 1) << 10) + q0 + w * 32 + ln];
        unsigned long long m11 = bp[((size_t)(t64b + 1) << 10) + q0 + w * 32 + 16 + ln];
        #pragma unroll
        for (int i = 0; i < 2; i++) {             // stage 2 sub-tiles (K and V)
            int tK = t0 + i * 64 + w * 8 + r8;
            dma16(Kp + (size_t)tK * 64 + kc * 8,
                  (char*)KsU + (size_t)(i * 512 + w * 64) * 16);
            int e = w * 8 + r8;
            dma16(Vp + (size_t)e * 1024 + t0 + i * 64 + kc * 8,
                  (char*)VsU + (size_t)(i * 512 + w * 64) * 16);
        }
        __syncthreads();                          // dma drained (vmcnt0 @ barrier)

        #pragma unroll
        for (int s = 0; s < 2; s++) {             // barrier-free: 2 sub-pipelines
            unsigned long long mcur0 = s ? m10 : m00;
            unsigned long long mcur1 = s ? m11 : m01;
            const uint4* Ks = KsU + s * 512;
            const uint4* Vs = VsU + s * 512;

            floatx4 st[2][4];
            #pragma unroll
            for (int g = 0; g < 2; g++)
                #pragma unroll
                for (int i = 0; i < 4; i++) st[g][i] = (floatx4){0.f, 0.f, 0.f, 0.f};
            __builtin_amdgcn_s_setprio(1);
            #pragma unroll
            for (int kk = 0; kk < 2; kk++) {
                #pragma unroll
                for (int tt = 0; tt < 4; tt++) {
                    short8 kf = as_frag(Ks[swz(tt * 16 + ln, kk * 4 + quad)]);
                    st[0][tt] = mfma16(kf, qf[0][kk], st[0][tt]);
                    st[1][tt] = mfma16(kf, qf[1][kk], st[1][tt]);
                }
            }
            __builtin_amdgcn_s_setprio(0);

            #pragma unroll
            for (int g = 0; g < 2; g++) {
                int qloc = g * 16 + ln;
                unsigned long long msh = (g ? mcur1 : mcur0) >> (quad * 4);
                #pragma unroll
                for (int tt = 0; tt < 4; tt++) {
                    unsigned mb = (unsigned)(msh >> (tt * 16)) & 0xFu;
                    float pe0 = (mb & 1u) ? 0.f : __builtin_amdgcn_exp2f(st[g][tt][0]);
                    float pe1 = (mb & 2u) ? 0.f : __builtin_amdgcn_exp2f(st[g][tt][1]);
                    float pe2 = (mb & 4u) ? 0.f : __builtin_amdgcn_exp2f(st[g][tt][2]);
                    float pe3 = (mb & 8u) ? 0.f : __builtin_amdgcn_exp2f(st[g][tt][3]);
                    lsum[g] += (pe0 + pe1) + (pe2 + pe3);
                    int kcp = tt * 2 + (quad >> 1);           // logical chunk of col
                    int off = qloc * 64 + (kcp ^ (qloc & 7)) * 8 + (quad & 1) * 4;
                    *(uint2*)(Pw + off) = pack4(pe0, pe1, pe2, pe3);
                }
            }

            __builtin_amdgcn_s_setprio(1);
            #pragma unroll
            for (int kk = 0; kk < 2; kk++) {
                short8 pf0 = as_frag(PsU[w * 256 + swz(0 * 16 + ln, kk * 4 + quad)]);
                short8 pf1 = as_frag(PsU[w * 256 + swz(1 * 16 + ln, kk * 4 + quad)]);
                #pragma unroll
                for (int et = 0; et < 4; et++) {
                    short8 vf = as_frag(Vs[swz(et * 16 + ln, kk * 4 + quad)]);
                    acc_o[0][et] = mfma16(vf, pf0, acc_o[0][et]);
                    acc_o[1][et] = mfma16(vf, pf1, acc_o[1][et]);
                }
            }
            __builtin_amdgcn_s_setprio(0);
        }
    }

    #pragma unroll
    for (int g = 0; g < 2; g++) {
        lsum[g] += __shfl_xor(lsum[g], 16, 64);
        lsum[g] += __shfl_xor(lsum[g], 32, 64);
    }

    #pragma unroll
    for (int g = 0; g < 2; g++) {
        float inv = 1.f / fmaxf(lsum[g], 1e-20f);
        int s = q0 + w * 32 + g * 16 + ln;
        __hip_bfloat16* crow = ctx + ((size_t)b * 1024 + s) * 1024 + h * 64 + quad * 4;
        #pragma unroll
        for (int et = 0; et < 4; et++) {
            uint2 pk = pack4(acc_o[g][et][0] * inv, acc_o[g][et][1] * inv,
                             acc_o[g][et][2] * inv, acc_o[g][et][3] * inv);
            *(uint2*)(crow + et * 16) = pk;
        }
    }
}

// ---------------------------------------------------------------- out GEMM (DMA)
// 128x128 tiles, grid (64,8) = 512 blocks = 2/CU; 2x2 waves (wave = 64m x 64n).
__global__ __launch_bounds__(256) void out_gemm_dma(
    const __hip_bfloat16* __restrict__ Cx,   // ctx [8192,1024]
    const __hip_bfloat16* __restrict__ WoT,  // [1024 n][1024 k]
    const __hip_bfloat16* __restrict__ bc,
    const unsigned* __restrict__ Xw,
    void* __restrict__ dout,
    int direct)
{
    __shared__ int s_is32;
    detect_mode(Xw, &s_is32);
    __shared__ uint4 AsU[128 * 8];
    __shared__ uint4 BsU[128 * 8];
    int tid = threadIdx.x, lane = tid & 63, wave = tid >> 6;
    int quad = lane >> 4, ln = lane & 15;
    int mw = wave & 1, nw = wave >> 1;
    int m0 = blockIdx.x * 128;
    int n0 = blockIdx.y * 128;

    floatx4 acc[4][4];
    #pragma unroll
    for (int i = 0; i < 4; i++)
        #pragma unroll
        for (int j = 0; j < 4; j++) acc[i][j] = (floatx4){0.f, 0.f, 0.f, 0.f};

    for (int k0 = 0; k0 < 1024; k0 += 64) {
        #pragma unroll
        for (int i = 0; i < 4; i++) {
            int r = wave * 32 + i * 8 + (lane >> 3);
            int kc = (lane & 7) ^ (r & 7);
            char* ldsA = (char*)AsU + (size_t)(wave * 256 + i * 64) * 16;
            char* ldsB = (char*)BsU + (size_t)(wave * 256 + i * 64) * 16;
            dma16(Cx + (size_t)(m0 + r) * 1024 + k0 + kc * 8, ldsA);
            dma16(WoT + (size_t)(n0 + r) * 1024 + k0 + kc * 8, ldsB);
        }
        __syncthreads();
        #pragma unroll
        for (int kk = 0; kk < 2; kk++) {
            short8 af[4], bfr[4];
            #pragma unroll
            for (int mi = 0; mi < 4; mi++)
                af[mi] = as_frag(AsU[swz(mw * 64 + mi * 16 + ln, kk * 4 + quad)]);
            #pragma unroll
            for (int ni = 0; ni < 4; ni++)
                bfr[ni] = as_frag(BsU[swz(nw * 64 + ni * 16 + ln, kk * 4 + quad)]);
            #pragma unroll
            for (int mi = 0; mi < 4; mi++)
                #pragma unroll
                for (int ni = 0; ni < 4; ni++)
                    acc[mi][ni] = mfma16(af[mi], bfr[ni], acc[mi][ni]);
        }
        __syncthreads();
    }

    const __hip_bfloat16* bo = bc + 3 * 1024;
    #pragma unroll
    for (int ni = 0; ni < 4; ni++) {
        int n = n0 + nw * 64 + ni * 16 + ln;
        float bval = __bfloat162float(bo[n]);
        #pragma unroll
        for (int mi = 0; mi < 4; mi++) {
            #pragma unroll
            for (int r = 0; r < 4; r++) {
                int m = m0 + mw * 64 + mi * 16 + quad * 4 + r;
                float v = acc[mi][ni][r] + bval;
                if (direct && s_is32) ((float*)dout)[(size_t)m * 1024 + n] = v;
                else ((__hip_bfloat16*)dout)[(size_t)m * 1024 + n] = __float2bfloat16(v);
            }
        }
    }
}

// ---------------------------------------------------------------- emit (fallback)
__global__ __launch_bounds__(256) void emit_out(
    const __hip_bfloat16* __restrict__ Fo, const unsigned* __restrict__ Xw,
    void* __restrict__ dout)
{
    __shared__ int s_is32;
    detect_mode(Xw, &s_is32);
    size_t g = (size_t)blockIdx.x * 256 + threadIdx.x;
    uint4 u = *(const uint4*)(Fo + g * 8);
    if (s_is32) {
        short8 s = __builtin_bit_cast(short8, u);
        float4 f0, f1;
        f0.x = b2f(s[0]); f0.y = b2f(s[1]); f0.z = b2f(s[2]); f0.w = b2f(s[3]);
        f1.x = b2f(s[4]); f1.y = b2f(s[5]); f1.z = b2f(s[6]); f1.w = b2f(s[7]);
        *(float4*)((float*)dout + g * 8) = f0;
        *(float4*)((float*)dout + g * 8 + 4) = f1;
    } else {
        *(uint4*)((__hip_bfloat16*)dout + g * 8) = u;
    }
}

// ---------------------------------------------------------------- launch
extern "C" void kernel_launch(void* const* d_in, const int* in_sizes, int n_in,
                              void* d_out, int out_size, void* d_ws, size_t ws_size,
                              hipStream_t stream) {
    const void* X  = d_in[0];
    const void* mk = d_in[1];
    const void* Wq = d_in[2];
    const void* bq = d_in[3];
    const void* Wk = d_in[4];
    const void* bk = d_in[5];
    const void* Wv = d_in[6];
    const void* bv = d_in[7];
    const void* Wo = d_in[8];
    const void* bo = d_in[9];
    const unsigned* Xw = (const unsigned*)X;

    char* ws = (char*)d_ws;
    __hip_bfloat16*     WT   = (__hip_bfloat16*)(ws);                        // [0, 6 MB)
    __hip_bfloat16*     WoT  = (__hip_bfloat16*)(ws + ((size_t)6 << 20));    // [6, 8 MB)
    unsigned long long* bits = (unsigned long long*)(ws + ((size_t)8 << 20));// [8, 9 MB)
    __hip_bfloat16*     bc   = (__hip_bfloat16*)(ws + ((size_t)9 << 20));    // [9, +8KB)
    __hip_bfloat16*     Xb   = (__hip_bfloat16*)(ws + ((size_t)10 << 20));   // [10, 26 MB)
    __hip_bfloat16*     Qb   = (__hip_bfloat16*)(ws + ((size_t)26 << 20));   // [26, 42 MB)
    __hip_bfloat16*     Kb   = (__hip_bfloat16*)(ws + ((size_t)42 << 20));   // [42, 58 MB)
    __hip_bfloat16*     Vtb  = (__hip_bfloat16*)(ws + ((size_t)58 << 20));   // [58, 74 MB)

    bool bigws = ws_size >= ((size_t)74 << 20);

    hipLaunchKernelGGL(prep_all, dim3(4609), dim3(256), 0, stream,
                       Wq, Wk, Wv, Wo, bq, bk, bv, bo, mk, X,
                       WT, WoT, bc, bits, Xb, bigws ? 1 : 0);

    if (bigws) {
        __hip_bfloat16* Cx = Xb;   // ctx reuses Xb (dead after qkv)
        hipLaunchKernelGGL(qkv_gemm_dma, dim3(32, 12), dim3(512), 0, stream,
                           Xb, WT, bc, Qb, Kb, Vtb);
        hipLaunchKernelGGL(attn, dim3(128, 4), dim3(512), 0, stream,
                           Qb, Kb, Vtb, bits, Cx);
        hipLaunchKernelGGL(out_gemm_dma, dim3(64, 8), dim3(256), 0, stream,
                           Cx, WoT, bc, Xw, d_out, 1);
    } else {
        __hip_bfloat16* Cx = (__hip_bfloat16*)d_out;   // ctx scratch in d_out
        __hip_bfloat16* Fo = Qb;                        // final bf16 over dead Q
        hipLaunchKernelGGL(qkv_gemm2, dim3(64, 24), dim3(256), 0, stream,
                           X, WT, bc, Qb, Kb, Vtb);
        hipLaunchKernelGGL(attn, dim3(128, 4), dim3(512), 0, stream,
                           Qb, Kb, Vtb, bits, Cx);
        hipLaunchKernelGGL(out_gemm_dma, dim3(64, 8), dim3(256), 0, stream,
                           Cx, WoT, bc, Xw, (void*)Fo, 0);
        hipLaunchKernelGGL(emit_out, dim3(4096), dim3(256), 0, stream,
                           Fo, Xw, d_out);
    }
}

// Round 11
// 285.275 us; speedup vs baseline: 1.0650x; 1.0487x over previous
//
#include <hip/hip_runtime.h>
#include <hip/hip_bf16.h>
#include <stdint.h>

// MultiHeadAttention: B=8, S=1024, D=1024, H=16, DH=64. fp32 in/out (auto-detects bf16).
// Round-19: REVERT to r16 best-measured config (289.6us) per pre-committed decision
// rule. The 8-phase 256^2 qkv (r17/r18) loses to the 2-phase even with 0 bank
// conflicts: grid 384 blocks @ 1 block/CU = 1.5 dispatch rounds (~25% tail) + 16
// barriers/K-tile with no cross-block overlap. 128^2 8-phase is the documented m232
// null quadrant. This problem's shape (M=8192,N=3072) doesn't tile 256^2 onto 256
// CUs cleanly -> 2-phase 256x128 @ 2-3 blocks/CU is the structure optimum here.
// qkv 2-phase 256x128 dma (72us, MfmaUtil 28.7); attn de-lockstep 8w x 32q KVBLK=128
// with hoisted masks (71.5us); prep mask-pack 1536 blocks; out 128^2 grid(64,8).
// ws layout A (>=74MB): WT@0(6) WoT@6(2) bits@8(1) bc@9 Xb@10(16,reused as ctx) Q@26 K@42 Vt@58
// ws layout B (<74MB):  raw-X fallback gemm; ctx in d_out; emit kernel.

typedef __attribute__((ext_vector_type(8))) short short8;
typedef __attribute__((ext_vector_type(4))) float floatx4;

#define C2S 0.04508422f   // (1/sqrt(1024)) * log2(e), folded into Q

__device__ __forceinline__ int swz(int r, int kc) { return r * 8 + (kc ^ (r & 7)); }
__device__ __forceinline__ short8 as_frag(uint4 u) { return __builtin_bit_cast(short8, u); }
__device__ __forceinline__ floatx4 mfma16(short8 a, short8 b, floatx4 c) {
    return __builtin_amdgcn_mfma_f32_16x16x32_bf16(a, b, c, 0, 0, 0);
}
__device__ __forceinline__ unsigned short f2bu(float f) {
    return __builtin_bit_cast(unsigned short, __float2bfloat16(f));
}
__device__ __forceinline__ short f2b(float f) {
    return __builtin_bit_cast(short, __float2bfloat16(f));
}
__device__ __forceinline__ float b2f(short s) {
    return __bfloat162float(__builtin_bit_cast(__hip_bfloat16, s));
}
// async global->LDS DMA, 16B per lane; lds dest = wave-uniform base + lane*16
__device__ __forceinline__ void dma16(const void* g, void* l) {
    __builtin_amdgcn_global_load_lds(
        (const __attribute__((address_space(1))) uint32_t*)g,
        (__attribute__((address_space(3))) uint32_t*)l, 16, 0, 0);
}
__device__ __forceinline__ uint2 pack4(float a, float b, float c, float d) {
    uint2 p;
    p.x = (unsigned)f2bu(a) | ((unsigned)f2bu(b) << 16);
    p.y = (unsigned)f2bu(c) | ((unsigned)f2bu(d) << 16);
    return p;
}

// Runtime dtype detection: bf16 data has sane exponents in the LOW halves of
// 32-bit words; fp32 data has uniform mantissa bits there.
__device__ __forceinline__ void detect_mode(const unsigned* Xw, int* s_is32) {
    if (threadIdx.x < 64) {
        unsigned lo = Xw[threadIdx.x] & 0xFFFFu;
        unsigned e = (lo >> 7) & 0xFFu;
        unsigned long long bal = __ballot(e >= 88u && e <= 150u);
        if (threadIdx.x == 0) *s_is32 = (bal != ~0ull) ? 1 : 0;
    }
    __syncthreads();
}

__device__ __forceinline__ float load_elt(const void* p, size_t idx, int is32) {
    return is32 ? ((const float*)p)[idx]
                : __bfloat162float(((const __hip_bfloat16*)p)[idx]);
}

// ---------------------------------------------------------------- fused prep
// blocks [0,1024): weight transpose (vectorized); [1024]: biases;
// [1025,2561): mask pack (t-major, 1536 blocks); [2561,4609): X convert.
__global__ __launch_bounds__(256) void prep_all(
    const void* __restrict__ Wq, const void* __restrict__ Wk,
    const void* __restrict__ Wv, const void* __restrict__ Wo,
    const void* __restrict__ bq, const void* __restrict__ bk,
    const void* __restrict__ bv, const void* __restrict__ bo,
    const void* __restrict__ mask_raw, const void* __restrict__ X,
    __hip_bfloat16* __restrict__ WT, __hip_bfloat16* __restrict__ WoT,
    __hip_bfloat16* __restrict__ bc, unsigned long long* __restrict__ bits64,
    __hip_bfloat16* __restrict__ Xb, int do_x)
{
    __shared__ __hip_bfloat16 T[64][72];
    __shared__ int s_is32;
    int blk = blockIdx.x;
    int tid = threadIdx.x;
    const unsigned* Xw = (const unsigned*)X;

    if (blk < 1024) {                           // ---- weight transpose (vectorized)
        detect_mode(Xw, &s_is32);
        const void* src; size_t src_off;
        __hip_bfloat16* dst;
        int src_ld, dst_ld;
        if (blk < 768) {                        // Wq/Wk/Wv: [h][d][e] -> WT[(p,h,e)][d]
            int p = blk >> 8;
            int rem = blk & 255;
            int h = rem >> 4, dt = rem & 15;
            src = (p == 0) ? Wq : (p == 1) ? Wk : Wv;
            src_off = ((size_t)h * 1024 + (size_t)dt * 64) * 64;
            dst = WT + (((size_t)p * 16 + h) * 64) * 1024 + dt * 64;
            src_ld = 64; dst_ld = 1024;
        } else {                                // Wo: [k][n] -> WoT[n][k]
            int t = blk - 768;
            int kt = t >> 4, nt = t & 15;
            src = Wo; src_off = (size_t)kt * 64 * 1024 + nt * 64;
            dst = WoT + (size_t)nt * 64 * 1024 + kt * 64;
            src_ld = 1024; dst_ld = 1024;
        }
        #pragma unroll
        for (int i = 0; i < 2; i++) {
            int seg = tid + i * 256;
            int r = seg >> 3, c0 = (seg & 7) * 8;
            if (s_is32) {
                const float* sf = (const float*)src + src_off + (size_t)r * src_ld + c0;
                float4 f0 = *(const float4*)sf;
                float4 f1 = *(const float4*)(sf + 4);
                T[c0 + 0][r] = __float2bfloat16(f0.x);
                T[c0 + 1][r] = __float2bfloat16(f0.y);
                T[c0 + 2][r] = __float2bfloat16(f0.z);
                T[c0 + 3][r] = __float2bfloat16(f0.w);
                T[c0 + 4][r] = __float2bfloat16(f1.x);
                T[c0 + 5][r] = __float2bfloat16(f1.y);
                T[c0 + 6][r] = __float2bfloat16(f1.z);
                T[c0 + 7][r] = __float2bfloat16(f1.w);
            } else {
                const __hip_bfloat16* sh =
                    (const __hip_bfloat16*)src + src_off + (size_t)r * src_ld + c0;
                uint4 u = *(const uint4*)sh;
                short8 s8 = __builtin_bit_cast(short8, u);
                #pragma unroll
                for (int j = 0; j < 8; j++)
                    T[c0 + j][r] = __builtin_bit_cast(__hip_bfloat16, (short)s8[j]);
            }
        }
        __syncthreads();
        #pragma unroll
        for (int i = 0; i < 2; i++) {
            int seg = tid + i * 256;
            int r = seg >> 3, c0 = (seg & 7) * 8;
            *(uint4*)(dst + (size_t)r * dst_ld + c0) = *(const uint4*)(&T[r][c0]);
        }
    } else if (blk == 1024) {                   // ---- biases (bq prescaled by C2S)
        detect_mode(Xw, &s_is32);
        #pragma unroll
        for (int i = 0; i < 16; i++) {
            int idx = tid + i * 256;
            int which = idx >> 10, j = idx & 1023;
            const void* src = (which == 0) ? bq : (which == 1) ? bk : (which == 2) ? bv : bo;
            float v = load_elt(src, j, s_is32);
            if (which == 0) v *= C2S;
            bc[idx] = __float2bfloat16(v);
        }
    } else if (blk < 2561) {                    // ---- mask pack (1536 blocks), t-major out
        int blkL = blk - 1025;
        const int* mi = (const int*)mask_raw;
        const unsigned char* mb = (const unsigned char*)mask_raw;
        int lane = tid & 63;
        bool ok = true;
        #pragma unroll
        for (int i = 0; i < 4; i++) {
            unsigned v = (unsigned)mi[lane * 4 + i];
            if (v > 1u) ok = false;
        }
        bool is_i32 = (__ballot(ok) == ~0ull);
        int gw = (blkL * 256 + tid) >> 6;
        const int NW = 1536 * 4;
        const int NWORDS = (8 * 1024 * 1024) / 64;
        // src word i = (b*1024 + q)*16 + t  ->  dst (b*16 + t)*1024 + q
        if (is_i32) {
            for (int i = gw; i < NWORDS; i += NW) {
                int mv = mi[(size_t)i * 64 + lane];
                unsigned long long bal = __ballot(mv != 0);
                if (lane == 0) {
                    int bb = i >> 14, q = (i >> 4) & 1023, t = i & 15;
                    bits64[((size_t)bb << 14) + ((size_t)t << 10) + q] = bal;
                }
            }
        } else {
            for (int i = gw; i < NWORDS; i += NW) {
                int mv = mb[(size_t)i * 64 + lane];
                unsigned long long bal = __ballot(mv != 0);
                if (lane == 0) {
                    int bb = i >> 14, q = (i >> 4) & 1023, t = i & 15;
                    bits64[((size_t)bb << 14) + ((size_t)t << 10) + q] = bal;
                }
            }
        }
    } else if (do_x) {                          // ---- X convert (2048 blocks)
        detect_mode(Xw, &s_is32);
        int blkL = blk - 2561;
        size_t g = ((size_t)blkL * 256 + tid) * 16;
        if (s_is32) {
            const float* Xf = (const float*)X;
            #pragma unroll
            for (int half = 0; half < 2; half++) {
                float4 f0 = *(const float4*)(Xf + g + half * 8);
                float4 f1 = *(const float4*)(Xf + g + half * 8 + 4);
                short8 s;
                s[0] = f2b(f0.x); s[1] = f2b(f0.y); s[2] = f2b(f0.z); s[3] = f2b(f0.w);
                s[4] = f2b(f1.x); s[5] = f2b(f1.y); s[6] = f2b(f1.z); s[7] = f2b(f1.w);
                *(uint4*)(Xb + g + half * 8) = __builtin_bit_cast(uint4, s);
            }
        } else {
            const uint4* Xu = (const uint4*)X;
            *(uint4*)(Xb + g)     = Xu[g / 8];
            *(uint4*)(Xb + g + 8) = Xu[g / 8 + 1];
        }
    }
}

// ---------------------------------------------------------------- QKV GEMM (DMA)
// C[8192 m, 3072 n] = Xb @ WT^T. 256x128 tiles, grid (32 m, 24 n).
// 2x2 wave grid: wave (mw,nw) covers 128m x 64n -> 24 b128 reads / 64 MFMA per iter.
// proj-0 (Q) output prescaled by C2S (bias already scaled in bc).
__global__ __launch_bounds__(256, 2) void qkv_gemm_dma(
    const __hip_bfloat16* __restrict__ Xb,   // [8192][1024] bf16
    const __hip_bfloat16* __restrict__ WT,   // [3072 n][1024 k]
    const __hip_bfloat16* __restrict__ bc,   // [4][1024]
    __hip_bfloat16* __restrict__ Q,
    __hip_bfloat16* __restrict__ Ko,
    __hip_bfloat16* __restrict__ Vt)
{
    __shared__ uint4 AsU[256 * 8];   // 32 KB
    __shared__ uint4 BsU[128 * 8];   // 16 KB
    int tid = threadIdx.x, lane = tid & 63, wave = tid >> 6;
    int quad = lane >> 4, ln = lane & 15;
    int mw = wave & 1, nw = wave >> 1;
    int m0 = blockIdx.x * 256;
    int n0 = blockIdx.y * 128;
    const __hip_bfloat16* Wp = WT + (size_t)n0 * 1024;

    floatx4 acc[8][4];
    #pragma unroll
    for (int i = 0; i < 8; i++)
        #pragma unroll
        for (int j = 0; j < 4; j++) acc[i][j] = (floatx4){0.f, 0.f, 0.f, 0.f};

    for (int k0 = 0; k0 < 1024; k0 += 64) {
        #pragma unroll
        for (int i = 0; i < 8; i++) {          // A: 2048 chunks
            int r = wave * 64 + i * 8 + (lane >> 3);
            int kc = (lane & 7) ^ (r & 7);
            char* lds = (char*)AsU + (size_t)(wave * 512 + i * 64) * 16;
            dma16(Xb + (size_t)(m0 + r) * 1024 + k0 + kc * 8, lds);
        }
        #pragma unroll
        for (int i = 0; i < 4; i++) {          // B: 1024 chunks
            int r = wave * 32 + i * 8 + (lane >> 3);
            int kc = (lane & 7) ^ (r & 7);
            char* lds = (char*)BsU + (size_t)(wave * 256 + i * 64) * 16;
            dma16(Wp + (size_t)r * 1024 + k0 + kc * 8, lds);
        }
        __syncthreads();
        #pragma unroll
        for (int kk = 0; kk < 2; kk++) {
            short8 af[8], bf[4];
            #pragma unroll
            for (int mi = 0; mi < 8; mi++)
                af[mi] = as_frag(AsU[swz(mw * 128 + mi * 16 + ln, kk * 4 + quad)]);
            #pragma unroll
            for (int ni = 0; ni < 4; ni++)
                bf[ni] = as_frag(BsU[swz(nw * 64 + ni * 16 + ln, kk * 4 + quad)]);
            #pragma unroll
            for (int mi = 0; mi < 8; mi++)
                #pragma unroll
                for (int ni = 0; ni < 4; ni++)
                    acc[mi][ni] = mfma16(af[mi], bf[ni], acc[mi][ni]);
        }
        __syncthreads();
    }

    int b = m0 >> 10;
    int s0 = m0 & 1023;
    int proj = n0 >> 10;                     // uniform per block
    if (proj == 2) {
        #pragma unroll
        for (int ni = 0; ni < 4; ni++) {
            int n = n0 + nw * 64 + ni * 16 + ln;
            int h = (n >> 6) & 15, e = n & 63;
            float bval = __bfloat162float(bc[2 * 1024 + (n & 1023)]);
            #pragma unroll
            for (int mi = 0; mi < 8; mi++) {
                int sb = s0 + mw * 128 + mi * 16 + quad * 4;
                uint2 pk = pack4(acc[mi][ni][0] + bval, acc[mi][ni][1] + bval,
                                 acc[mi][ni][2] + bval, acc[mi][ni][3] + bval);
                *(uint2*)(Vt + (((size_t)b * 16 + h) * 64 + e) * 1024 + sb) = pk;
            }
        }
    } else {
        __hip_bfloat16* P = (proj == 0) ? Q : Ko;
        float sc = (proj == 0) ? C2S : 1.f;   // fold attn scale*log2e into Q
        #pragma unroll
        for (int ni = 0; ni < 4; ni++) {
            int n = n0 + nw * 64 + ni * 16 + ln;
            int h = (n >> 6) & 15, e = n & 63;
            float bval = __bfloat162float(bc[proj * 1024 + (n & 1023)]);
            #pragma unroll
            for (int mi = 0; mi < 8; mi++) {
                #pragma unroll
                for (int r = 0; r < 4; r++) {
                    int s = s0 + mw * 128 + mi * 16 + quad * 4 + r;
                    P[(((size_t)b * 16 + h) * 1024 + s) * 64 + e] =
                        __float2bfloat16(acc[mi][ni][r] * sc + bval);
                }
            }
        }
    }
}

// ---------------------------------------------------------------- QKV GEMM (fallback, raw X)
__global__ __launch_bounds__(256) void qkv_gemm2(
    const void* __restrict__ Xsrc,
    const __hip_bfloat16* __restrict__ WT,
    const __hip_bfloat16* __restrict__ bc,
    __hip_bfloat16* __restrict__ Q,
    __hip_bfloat16* __restrict__ Ko,
    __hip_bfloat16* __restrict__ Vt)
{
    __shared__ int s_is32;
    detect_mode((const unsigned*)Xsrc, &s_is32);
    __shared__ uint4 AsU[128 * 8];
    __shared__ uint4 BsU[128 * 8];
    int tid = threadIdx.x, lane = tid & 63, wave = tid >> 6;
    int quad = lane >> 4, ln = lane & 15;
    int m0 = blockIdx.x * 128;
    int n0 = blockIdx.y * 128;
    const __hip_bfloat16* Wp = WT + (size_t)n0 * 1024;
    const float* Xf = (const float*)Xsrc;
    const __hip_bfloat16* Xh = (const __hip_bfloat16*)Xsrc;

    floatx4 acc[2][8];
    #pragma unroll
    for (int i = 0; i < 2; i++)
        #pragma unroll
        for (int j = 0; j < 8; j++) acc[i][j] = (floatx4){0.f, 0.f, 0.f, 0.f};

    for (int k0 = 0; k0 < 1024; k0 += 64) {
        if (s_is32) {
            #pragma unroll
            for (int i = 0; i < 4; i++) {
                int id = tid + i * 256;
                int r = id >> 3, kc = id & 7;
                size_t off = (size_t)(m0 + r) * 1024 + k0 + kc * 8;
                float4 f0 = *(const float4*)(Xf + off);
                float4 f1 = *(const float4*)(Xf + off + 4);
                short8 s;
                s[0] = f2b(f0.x); s[1] = f2b(f0.y); s[2] = f2b(f0.z); s[3] = f2b(f0.w);
                s[4] = f2b(f1.x); s[5] = f2b(f1.y); s[6] = f2b(f1.z); s[7] = f2b(f1.w);
                AsU[swz(r, kc)] = __builtin_bit_cast(uint4, s);
            }
        } else {
            #pragma unroll
            for (int i = 0; i < 4; i++) {
                int id = tid + i * 256;
                int r = id >> 3, kc = id & 7;
                AsU[swz(r, kc)] = *(const uint4*)(Xh + (size_t)(m0 + r) * 1024 + k0 + kc * 8);
            }
        }
        #pragma unroll
        for (int i = 0; i < 4; i++) {
            int id = tid + i * 256;
            int r = id >> 3, kc = id & 7;
            BsU[swz(r, kc)] = *(const uint4*)(Wp + (size_t)r * 1024 + k0 + kc * 8);
        }
        __syncthreads();
        #pragma unroll
        for (int kk = 0; kk < 2; kk++) {
            short8 a0 = as_frag(AsU[swz(wave * 32 + ln, kk * 4 + quad)]);
            short8 a1 = as_frag(AsU[swz(wave * 32 + 16 + ln, kk * 4 + quad)]);
            #pragma unroll
            for (int nt = 0; nt < 8; nt++) {
                short8 bfr = as_frag(BsU[swz(nt * 16 + ln, kk * 4 + quad)]);
                acc[0][nt] = mfma16(a0, bfr, acc[0][nt]);
                acc[1][nt] = mfma16(a1, bfr, acc[1][nt]);
            }
        }
        __syncthreads();
    }

    int b = m0 >> 10;
    int s0 = m0 & 1023;
    #pragma unroll
    for (int nt = 0; nt < 8; nt++) {
        int n = n0 + nt * 16 + ln;
        int proj = n >> 10, h = (n >> 6) & 15, e = n & 63;
        float bval = __bfloat162float(bc[proj * 1024 + (n & 1023)]);
        float sc = (proj == 0) ? C2S : 1.f;
        #pragma unroll
        for (int mt = 0; mt < 2; mt++) {
            #pragma unroll
            for (int r = 0; r < 4; r++) {
                int s = s0 + wave * 32 + mt * 16 + quad * 4 + r;
                float v = acc[mt][nt][r] * sc + bval;
                if (proj == 2) {
                    Vt[(((size_t)b * 16 + h) * 64 + e) * 1024 + s] = __float2bfloat16(v);
                } else {
                    __hip_bfloat16* P = (proj == 0) ? Q : Ko;
                    P[(((size_t)b * 16 + h) * 1024 + s) * 64 + e] = __float2bfloat16(v);
                }
            }
        }
    }
}

// ---------------------------------------------------------------- attention
// grid (128, 4): x = bh (XCD-colocated), y = 256-row Q tile. 8 waves x 32 q-rows.
// Operand-swapped: S^T = K Q^T, O^T = V^T P^T. Q-frags direct from global (no Q LDS).
// KVBLK=128: stage K/V once per 128 t (sync; dma; sync), then 2 barrier-free
// sub-tile pipelines per stretch (P is per-wave). Q prescaled by C2S -> P = exp2(st).
// Mask loads for BOTH sub-tiles hoisted above the dma issue. LDS 64 KB -> 2 blocks/CU.
__global__ __launch_bounds__(512, 4) void attn(
    const __hip_bfloat16* __restrict__ Q,
    const __hip_bfloat16* __restrict__ K,
    const __hip_bfloat16* __restrict__ Vt,
    const unsigned long long* __restrict__ bits,  // [8][16 t][1024 q]
    __hip_bfloat16* __restrict__ ctx)             // [8][1024][1024]
{
    __shared__ uint4 KsU[2 * 512];                // 16 KB (2 sub-tiles of 64t x 64e)
    __shared__ uint4 VsU[2 * 512];                // 16 KB (2 sub-tiles of 64e x 64t)
    __shared__ uint4 PsU[8 * 256];                // 32 KB (8 waves x 32q x 8 chunks)

    int tid = threadIdx.x, lane = tid & 63, w = tid >> 6;   // w in {0..7}
    int quad = lane >> 4, ln = lane & 15;
    int bh = blockIdx.x;
    int q0 = blockIdx.y * 256;
    int b = bh >> 4, h = bh & 15;
    const __hip_bfloat16* Qp = Q + (size_t)bh * 1024 * 64;
    const __hip_bfloat16* Kp = K + (size_t)bh * 1024 * 64;
    const __hip_bfloat16* Vp = Vt + (size_t)bh * 64 * 1024;
    const unsigned long long* bp = bits + (size_t)b * 16 * 1024;

    short8 qf[2][2];
    #pragma unroll
    for (int g = 0; g < 2; g++)
        #pragma unroll
        for (int kk = 0; kk < 2; kk++)
            qf[g][kk] = as_frag(*(const uint4*)(
                Qp + (size_t)(q0 + w * 32 + g * 16 + ln) * 64 + kk * 32 + quad * 8));

    int r8 = lane >> 3;                 // 0..7  (== r&7 since w*8 ≡ 0 mod 8)
    int kc = (lane & 7) ^ r8;           // swizzled source chunk (loop-invariant)

    floatx4 acc_o[2][4];                          // [qg][e-tile]
    #pragma unroll
    for (int g = 0; g < 2; g++)
        #pragma unroll
        for (int i = 0; i < 4; i++) acc_o[g][i] = (floatx4){0.f, 0.f, 0.f, 0.f};
    float lsum[2] = {0.f, 0.f};
    __hip_bfloat16* Pw = (__hip_bfloat16*)&PsU[w * 256];

    for (int t0 = 0; t0 < 1024; t0 += 128) {
        __syncthreads();                          // prior-stretch K/V reads done
        int t64b = t0 >> 6;
        unsigned long long m00 = bp[((size_t)t64b << 10) + q0 + w * 32 + ln];
        unsigned long long m01 = bp[((size_t)t64b << 10) + q0 + w * 32 + 16 + ln];
        unsigned long long m10 = bp[((size_t)(t64b + 1) << 10) + q0 + w * 32 + ln];
        unsigned long long m11 = bp[((size_t)(t64b + 1) << 10) + q0 + w * 32 + 16 + ln];
        #pragma unroll
        for (int i = 0; i < 2; i++) {             // stage 2 sub-tiles (K and V)
            int tK = t0 + i * 64 + w * 8 + r8;
            dma16(Kp + (size_t)tK * 64 + kc * 8,
                  (char*)KsU + (size_t)(i * 512 + w * 64) * 16);
            int e = w * 8 + r8;
            dma16(Vp + (size_t)e * 1024 + t0 + i * 64 + kc * 8,
                  (char*)VsU + (size_t)(i * 512 + w * 64) * 16);
        }
        __syncthreads();                          // dma drained (vmcnt0 @ barrier)

        #pragma unroll
        for (int s = 0; s < 2; s++) {             // barrier-free: 2 sub-pipelines
            unsigned long long mcur0 = s ? m10 : m00;
            unsigned long long mcur1 = s ? m11 : m01;
            const uint4* Ks = KsU + s * 512;
            const uint4* Vs = VsU + s * 512;

            floatx4 st[2][4];
            #pragma unroll
            for (int g = 0; g < 2; g++)
                #pragma unroll
                for (int i = 0; i < 4; i++) st[g][i] = (floatx4){0.f, 0.f, 0.f, 0.f};
            __builtin_amdgcn_s_setprio(1);
            #pragma unroll
            for (int kk = 0; kk < 2; kk++) {
                #pragma unroll
                for (int tt = 0; tt < 4; tt++) {
                    short8 kf = as_frag(Ks[swz(tt * 16 + ln, kk * 4 + quad)]);
                    st[0][tt] = mfma16(kf, qf[0][kk], st[0][tt]);
                    st[1][tt] = mfma16(kf, qf[1][kk], st[1][tt]);
                }
            }
            __builtin_amdgcn_s_setprio(0);

            #pragma unroll
            for (int g = 0; g < 2; g++) {
                int qloc = g * 16 + ln;
                unsigned long long msh = (g ? mcur1 : mcur0) >> (quad * 4);
                #pragma unroll
                for (int tt = 0; tt < 4; tt++) {
                    unsigned mb = (unsigned)(msh >> (tt * 16)) & 0xFu;
                    float pe0 = (mb & 1u) ? 0.f : __builtin_amdgcn_exp2f(st[g][tt][0]);
                    float pe1 = (mb & 2u) ? 0.f : __builtin_amdgcn_exp2f(st[g][tt][1]);
                    float pe2 = (mb & 4u) ? 0.f : __builtin_amdgcn_exp2f(st[g][tt][2]);
                    float pe3 = (mb & 8u) ? 0.f : __builtin_amdgcn_exp2f(st[g][tt][3]);
                    lsum[g] += (pe0 + pe1) + (pe2 + pe3);
                    int kcp = tt * 2 + (quad >> 1);           // logical chunk of col
                    int off = qloc * 64 + (kcp ^ (qloc & 7)) * 8 + (quad & 1) * 4;
                    *(uint2*)(Pw + off) = pack4(pe0, pe1, pe2, pe3);
                }
            }

            __builtin_amdgcn_s_setprio(1);
            #pragma unroll
            for (int kk = 0; kk < 2; kk++) {
                short8 pf0 = as_frag(PsU[w * 256 + swz(0 * 16 + ln, kk * 4 + quad)]);
                short8 pf1 = as_frag(PsU[w * 256 + swz(1 * 16 + ln, kk * 4 + quad)]);
                #pragma unroll
                for (int et = 0; et < 4; et++) {
                    short8 vf = as_frag(Vs[swz(et * 16 + ln, kk * 4 + quad)]);
                    acc_o[0][et] = mfma16(vf, pf0, acc_o[0][et]);
                    acc_o[1][et] = mfma16(vf, pf1, acc_o[1][et]);
                }
            }
            __builtin_amdgcn_s_setprio(0);
        }
    }

    #pragma unroll
    for (int g = 0; g < 2; g++) {
        lsum[g] += __shfl_xor(lsum[g], 16, 64);
        lsum[g] += __shfl_xor(lsum[g], 32, 64);
    }

    #pragma unroll
    for (int g = 0; g < 2; g++) {
        float inv = 1.f / fmaxf(lsum[g], 1e-20f);
        int s = q0 + w * 32 + g * 16 + ln;
        __hip_bfloat16* crow = ctx + ((size_t)b * 1024 + s) * 1024 + h * 64 + quad * 4;
        #pragma unroll
        for (int et = 0; et < 4; et++) {
            uint2 pk = pack4(acc_o[g][et][0] * inv, acc_o[g][et][1] * inv,
                             acc_o[g][et][2] * inv, acc_o[g][et][3] * inv);
            *(uint2*)(crow + et * 16) = pk;
        }
    }
}

// ---------------------------------------------------------------- out GEMM (DMA)
// 128x128 tiles, grid (64,8) = 512 blocks = 2/CU; 2x2 waves (wave = 64m x 64n).
__global__ __launch_bounds__(256) void out_gemm_dma(
    const __hip_bfloat16* __restrict__ Cx,   // ctx [8192,1024]
    const __hip_bfloat16* __restrict__ WoT,  // [1024 n][1024 k]
    const __hip_bfloat16* __restrict__ bc,
    const unsigned* __restrict__ Xw,
    void* __restrict__ dout,
    int direct)
{
    __shared__ int s_is32;
    detect_mode(Xw, &s_is32);
    __shared__ uint4 AsU[128 * 8];
    __shared__ uint4 BsU[128 * 8];
    int tid = threadIdx.x, lane = tid & 63, wave = tid >> 6;
    int quad = lane >> 4, ln = lane & 15;
    int mw = wave & 1, nw = wave >> 1;
    int m0 = blockIdx.x * 128;
    int n0 = blockIdx.y * 128;

    floatx4 acc[4][4];
    #pragma unroll
    for (int i = 0; i < 4; i++)
        #pragma unroll
        for (int j = 0; j < 4; j++) acc[i][j] = (floatx4){0.f, 0.f, 0.f, 0.f};

    for (int k0 = 0; k0 < 1024; k0 += 64) {
        #pragma unroll
        for (int i = 0; i < 4; i++) {
            int r = wave * 32 + i * 8 + (lane >> 3);
            int kc = (lane & 7) ^ (r & 7);
            char* ldsA = (char*)AsU + (size_t)(wave * 256 + i * 64) * 16;
            char* ldsB = (char*)BsU + (size_t)(wave * 256 + i * 64) * 16;
            dma16(Cx + (size_t)(m0 + r) * 1024 + k0 + kc * 8, ldsA);
            dma16(WoT + (size_t)(n0 + r) * 1024 + k0 + kc * 8, ldsB);
        }
        __syncthreads();
        #pragma unroll
        for (int kk = 0; kk < 2; kk++) {
            short8 af[4], bfr[4];
            #pragma unroll
            for (int mi = 0; mi < 4; mi++)
                af[mi] = as_frag(AsU[swz(mw * 64 + mi * 16 + ln, kk * 4 + quad)]);
            #pragma unroll
            for (int ni = 0; ni < 4; ni++)
                bfr[ni] = as_frag(BsU[swz(nw * 64 + ni * 16 + ln, kk * 4 + quad)]);
            #pragma unroll
            for (int mi = 0; mi < 4; mi++)
                #pragma unroll
                for (int ni = 0; ni < 4; ni++)
                    acc[mi][ni] = mfma16(af[mi], bfr[ni], acc[mi][ni]);
        }
        __syncthreads();
    }

    const __hip_bfloat16* bo = bc + 3 * 1024;
    #pragma unroll
    for (int ni = 0; ni < 4; ni++) {
        int n = n0 + nw * 64 + ni * 16 + ln;
        float bval = __bfloat162float(bo[n]);
        #pragma unroll
        for (int mi = 0; mi < 4; mi++) {
            #pragma unroll
            for (int r = 0; r < 4; r++) {
                int m = m0 + mw * 64 + mi * 16 + quad * 4 + r;
                float v = acc[mi][ni][r] + bval;
                if (direct && s_is32) ((float*)dout)[(size_t)m * 1024 + n] = v;
                else ((__hip_bfloat16*)dout)[(size_t)m * 1024 + n] = __float2bfloat16(v);
            }
        }
    }
}

// ---------------------------------------------------------------- emit (fallback)
__global__ __launch_bounds__(256) void emit_out(
    const __hip_bfloat16* __restrict__ Fo, const unsigned* __restrict__ Xw,
    void* __restrict__ dout)
{
    __shared__ int s_is32;
    detect_mode(Xw, &s_is32);
    size_t g = (size_t)blockIdx.x * 256 + threadIdx.x;
    uint4 u = *(const uint4*)(Fo + g * 8);
    if (s_is32) {
        short8 s = __builtin_bit_cast(short8, u);
        float4 f0, f1;
        f0.x = b2f(s[0]); f0.y = b2f(s[1]); f0.z = b2f(s[2]); f0.w = b2f(s[3]);
        f1.x = b2f(s[4]); f1.y = b2f(s[5]); f1.z = b2f(s[6]); f1.w = b2f(s[7]);
        *(float4*)((float*)dout + g * 8) = f0;
        *(float4*)((float*)dout + g * 8 + 4) = f1;
    } else {
        *(uint4*)((__hip_bfloat16*)dout + g * 8) = u;
    }
}

// ---------------------------------------------------------------- launch
extern "C" void kernel_launch(void* const* d_in, const int* in_sizes, int n_in,
                              void* d_out, int out_size, void* d_ws, size_t ws_size,
                              hipStream_t stream) {
    const void* X  = d_in[0];
    const void* mk = d_in[1];
    const void* Wq = d_in[2];
    const void* bq = d_in[3];
    const void* Wk = d_in[4];
    const void* bk = d_in[5];
    const void* Wv = d_in[6];
    const void* bv = d_in[7];
    const void* Wo = d_in[8];
    const void* bo = d_in[9];
    const unsigned* Xw = (const unsigned*)X;

    char* ws = (char*)d_ws;
    __hip_bfloat16*     WT   = (__hip_bfloat16*)(ws);                        // [0, 6 MB)
    __hip_bfloat16*     WoT  = (__hip_bfloat16*)(ws + ((size_t)6 << 20));    // [6, 8 MB)
    unsigned long long* bits = (unsigned long long*)(ws + ((size_t)8 << 20));// [8, 9 MB)
    __hip_bfloat16*     bc   = (__hip_bfloat16*)(ws + ((size_t)9 << 20));    // [9, +8KB)
    __hip_bfloat16*     Xb   = (__hip_bfloat16*)(ws + ((size_t)10 << 20));   // [10, 26 MB)
    __hip_bfloat16*     Qb   = (__hip_bfloat16*)(ws + ((size_t)26 << 20));   // [26, 42 MB)
    __hip_bfloat16*     Kb   = (__hip_bfloat16*)(ws + ((size_t)42 << 20));   // [42, 58 MB)
    __hip_bfloat16*     Vtb  = (__hip_bfloat16*)(ws + ((size_t)58 << 20));   // [58, 74 MB)

    bool bigws = ws_size >= ((size_t)74 << 20);

    hipLaunchKernelGGL(prep_all, dim3(4609), dim3(256), 0, stream,
                       Wq, Wk, Wv, Wo, bq, bk, bv, bo, mk, X,
                       WT, WoT, bc, bits, Xb, bigws ? 1 : 0);

    if (bigws) {
        __hip_bfloat16* Cx = Xb;   // ctx reuses Xb (dead after qkv)
        hipLaunchKernelGGL(qkv_gemm_dma, dim3(32, 24), dim3(256), 0, stream,
                           Xb, WT, bc, Qb, Kb, Vtb);
        hipLaunchKernelGGL(attn, dim3(128, 4), dim3(512), 0, stream,
                           Qb, Kb, Vtb, bits, Cx);
        hipLaunchKernelGGL(out_gemm_dma, dim3(64, 8), dim3(256), 0, stream,
                           Cx, WoT, bc, Xw, d_out, 1);
    } else {
        __hip_bfloat16* Cx = (__hip_bfloat16*)d_out;   // ctx scratch in d_out
        __hip_bfloat16* Fo = Qb;                        // final bf16 over dead Q
        hipLaunchKernelGGL(qkv_gemm2, dim3(64, 24), dim3(256), 0, stream,
                           X, WT, bc, Qb, Kb, Vtb);
        hipLaunchKernelGGL(attn, dim3(128, 4), dim3(512), 0, stream,
                           Qb, Kb, Vtb, bits, Cx);
        hipLaunchKernelGGL(out_gemm_dma, dim3(64, 8), dim3(256), 0, stream,
                           Cx, WoT, bc, Xw, (void*)Fo, 0);
        hipLaunchKernelGGL(emit_out, dim3(4096), dim3(256), 0, stream,
                           Fo, Xw, d_out);
    }
}